// Round 14
// baseline (988.084 us; speedup 1.0000x reference)
//
#include <hip/hip_runtime.h>

#define KDIR 100
#define TILE 4096
#define NPASS 3
#define MBLK 256
#define MOUT 4096
#define MPT2 (MOUT / MBLK)

__device__ __forceinline__ unsigned encodeF(float f) {
  unsigned u = __float_as_uint(f);
  return u ^ ((u >> 31) ? 0xFFFFFFFFu : 0x80000000u);
}
__device__ __forceinline__ float decodeU(unsigned u) {
  return __uint_as_float(u ^ ((u >> 31) ? 0x80000000u : 0xFFFFFFFFu));
}

// tbl layout: [0..99]=cos, [128..227]=sin, [256..355]=c=(cos+sin)*invn, [384..483]=invn
// synthetic entry k=100: (0.5, 0.5, invn=1) -> diagonal key 0.5*(x+y)
__global__ void k_table(float* tbl, double* part, int nSlots) {
  int k = threadIdx.x;
  const double PI = 3.14159265358979323846;
  if (k < KDIR) {
    double th = -PI * 0.5 + (double)k * (PI / (double)KDIR);
    float c = (float)cos(th), s = (float)sin(th);
    float invn = 1.0f / (c * c + s * s);
    tbl[k] = c; tbl[128 + k] = s; tbl[256 + k] = (c + s) * invn; tbl[384 + k] = invn;
  }
  if (k == 100) { tbl[100] = 0.5f; tbl[228] = 0.5f; tbl[484] = 1.0f; }
  for (int i = k; i < nSlots; i += 256) part[i] = 0.0;
}

// Fused projection-build + pass-0 (shift=8) per-tile histogram.
// counts[((seg0+dir)*256 + d)*T + tile]
__global__ __launch_bounds__(256) void k_build(const float* __restrict__ P, int n, int kIdx,
                                               const float* __restrict__ tbl,
                                               unsigned* __restrict__ dst,
                                               unsigned* __restrict__ counts, int T, int seg0) {
  __shared__ unsigned h[256];
  int tid = threadIdx.x;
  h[tid] = 0;
  __syncthreads();
  int dir = blockIdx.y;
  int k = kIdx + dir;
  float ck = tbl[k], sk = tbl[128 + k], inv = tbl[384 + k];
  int tile = blockIdx.x;
  int start = tile * TILE;
  int nItems = min(TILE, n - start);
  unsigned* d0 = dst + (size_t)dir * n + start;
  const float* p0 = P + 2 * (size_t)start;
  if (nItems == TILE) {
    const float4* p4 = (const float4*)p0;
    uint2* o2 = (uint2*)d0;
#pragma unroll
    for (int i = 0; i < 8; ++i) {
      float4 v = p4[i * 256 + tid];
      unsigned ua = encodeF((v.x * ck + v.y * sk) * inv);
      unsigned ub = encodeF((v.z * ck + v.w * sk) * inv);
      o2[i * 256 + tid] = make_uint2(ua, ub);
      atomicAdd(&h[(ua >> 8) & 255u], 1u);
      atomicAdd(&h[(ub >> 8) & 255u], 1u);
    }
  } else {
    for (int j = tid; j < nItems; j += 256) {
      float x = p0[2 * j], y = p0[2 * j + 1];
      unsigned u = encodeF((x * ck + y * sk) * inv);
      d0[j] = u;
      atomicAdd(&h[(u >> 8) & 255u], 1u);
    }
  }
  __syncthreads();
  counts[((size_t)(seg0 + dir) * 256 + tid) * T + tile] = h[tid];
}

// Per-pass 8-bit histogram (passes 1,2); per-wave sub-histograms cut
// same-address LDS-atomic serialization.
__global__ __launch_bounds__(256) void k_hist8(const unsigned* __restrict__ keys,
                                               int L, int T, int shift,
                                               unsigned* __restrict__ counts) {
  __shared__ unsigned h[4][256];
  int tid = threadIdx.x;
  int w = tid >> 6;
  for (int i = tid; i < 4 * 256; i += 256) ((unsigned*)h)[i] = 0;
  __syncthreads();
  int seg = blockIdx.y, tile = blockIdx.x;
  const unsigned* base = keys + (size_t)seg * L + (size_t)tile * TILE;
  int nItems = min(TILE, L - tile * TILE);
  if (nItems == TILE) {
    const uint4* b4 = (const uint4*)base;
#pragma unroll
    for (int i = 0; i < 4; ++i) {
      uint4 v = b4[i * 256 + tid];
      atomicAdd(&h[w][(v.x >> shift) & 255u], 1u);
      atomicAdd(&h[w][(v.y >> shift) & 255u], 1u);
      atomicAdd(&h[w][(v.z >> shift) & 255u], 1u);
      atomicAdd(&h[w][(v.w >> shift) & 255u], 1u);
    }
  } else {
    for (int i = tid; i < nItems; i += 256)
      atomicAdd(&h[w][(base[i] >> shift) & 255u], 1u);
  }
  __syncthreads();
  counts[((size_t)seg * 256 + tid) * T + tile] =
      h[0][tid] + h[1][tid] + h[2][tid] + h[3][tid];
}

// Per-segment exclusive scan of [256*T] (digit-major): 256 threads, T elems each.
__global__ __launch_bounds__(256) void k_scanSeg(unsigned* __restrict__ counts, int T) {
  __shared__ unsigned tot[256];
  unsigned* c = counts + (size_t)blockIdx.x * 256 * T;
  int tid = threadIdx.x;
  int base = tid * T;
  unsigned sum = 0;
  for (int i = 0; i < T; ++i) sum += c[base + i];
  tot[tid] = sum;
  __syncthreads();
  for (int ofs = 1; ofs < 256; ofs <<= 1) {
    unsigned t = (tid >= ofs) ? tot[tid - ofs] : 0u;
    __syncthreads();
    tot[tid] += t;
    __syncthreads();
  }
  unsigned run = tot[tid] - sum;  // exclusive prefix of this thread's chunk
  for (int i = 0; i < T; ++i) {
    unsigned v = c[base + i];
    c[base + i] = run;
    run += v;
  }
}

// 8-bit scatter, STABLE, two-phase (rank -> LDS stage -> coalesced write).
// Fold is register-resident: 16 independent LDS reads -> reg scan -> 16
// independent writes (replaces the 16-step dependent LDS RMW chain).
__global__ __launch_bounds__(256) void k_scatter8(const unsigned* __restrict__ src,
                                                  unsigned* __restrict__ dst,
                                                  int L, int T, int shift,
                                                  const unsigned* __restrict__ counts) {
  __shared__ unsigned runG[4][4][256];  // [wave][group][digit]; reused as key stage
  __shared__ unsigned diffD[256];       // globalBase[d] - localStart[d]
  __shared__ unsigned wsum[4];
  int tid = threadIdx.x;
  int lane = tid & 63, w = tid >> 6;
  int seg = blockIdx.y, tile = blockIdx.x;
  const unsigned* sbase = src + (size_t)seg * L + (size_t)tile * TILE;
  int nItems = min(TILE, L - tile * TILE);
  for (int i = tid; i < 4 * 4 * 256; i += 256) ((unsigned*)runG)[i] = 0;
  __syncthreads();
  unsigned kk[16];
  unsigned rr[16];
  unsigned long long laneLT = (1ull << lane) - 1ull;
  int jbase = w * (TILE / 4);
#pragma unroll
  for (int i = 0; i < 16; ++i) {
    int j = jbase + i * 64 + lane;
    kk[i] = (j < nItems) ? sbase[j] : 0xFFFFFFFFu;
  }
#pragma unroll
  for (int s = 0; s < 4; ++s) {
    unsigned long long mask[4];
    unsigned prev[4];
#pragma unroll
    for (int g = 0; g < 4; ++g) {
      int i = g * 4 + s;
      int j = jbase + i * 64 + lane;
      bool valid = j < nItems;
      unsigned long long act = __ballot(valid);
      unsigned d = (kk[i] >> shift) & 255u;
      unsigned long long m = act;
#pragma unroll
      for (int b = 0; b < 8; ++b) {
        unsigned long long bal = __ballot((d >> b) & 1);
        m &= ((d >> b) & 1) ? bal : ~bal;
      }
      mask[g] = m;
      prev[g] = runG[w][g][d];
    }
#pragma unroll
    for (int g = 0; g < 4; ++g) {
      int i = g * 4 + s;
      int j = jbase + i * 64 + lane;
      if (j < nItems) {
        unsigned d = (kk[i] >> shift) & 255u;
        unsigned r = (unsigned)__popcll(mask[g] & laneLT);
        rr[i] = prev[g] + r;
        if (r == 0) runG[w][g][d] = prev[g] + (unsigned)__popcll(mask[g]);
      }
    }
  }
  __syncthreads();
  // register-resident fold: tid == digit
  {
    unsigned v[16];
#pragma unroll
    for (int w2 = 0; w2 < 4; ++w2)
#pragma unroll
      for (int g2 = 0; g2 < 4; ++g2) v[w2 * 4 + g2] = runG[w2][g2][tid];
    unsigned tot = 0;
#pragma unroll
    for (int i = 0; i < 16; ++i) {
      unsigned t = v[i];
      v[i] = tot;
      tot += t;
    }
    unsigned x = tot;
#pragma unroll
    for (int ofs = 1; ofs < 64; ofs <<= 1) {
      unsigned t = __shfl_up(x, ofs, 64);
      if (lane >= ofs) x += t;
    }
    if (lane == 63) wsum[w] = x;
    __syncthreads();
    unsigned basew = 0;
#pragma unroll
    for (int w2 = 0; w2 < 4; ++w2) basew += (w2 < w) ? wsum[w2] : 0u;
    unsigned localStart = basew + x - tot;
    diffD[tid] = counts[((size_t)seg * 256 + tid) * T + tile] - localStart;
#pragma unroll
    for (int w2 = 0; w2 < 4; ++w2)
#pragma unroll
      for (int g2 = 0; g2 < 4; ++g2)
        runG[w2][g2][tid] = v[w2 * 4 + g2] + localStart;
  }
  __syncthreads();
  unsigned lp[16];
#pragma unroll
  for (int i = 0; i < 16; ++i) {
    unsigned d = (kk[i] >> shift) & 255u;
    lp[i] = runG[w][i >> 2][d] + rr[i];
  }
  __syncthreads();
  unsigned* kbuf = &runG[0][0][0];  // 4096 u32
#pragma unroll
  for (int i = 0; i < 16; ++i) {
    int j = jbase + i * 64 + lane;
    if (j < nItems) kbuf[lp[i]] = kk[i];
  }
  __syncthreads();
  unsigned* dbase = dst + (size_t)seg * L;
#pragma unroll
  for (int i = 0; i < 16; ++i) {
    int pos = i * 256 + tid;
    if (pos < nItems) {
      unsigned k = kbuf[pos];
      unsigned d = (k >> shift) & 255u;
      dbase[diffD[d] + (unsigned)pos] = k;
    }
  }
}

__device__ __forceinline__ float scaledAt(const unsigned* __restrict__ s, int len, int j,
                                          float c, int rev) {
  return c * decodeU(s[rev ? (len - 1 - j) : j]);
}

__device__ int mergeSplit(const unsigned* __restrict__ U, int n,
                          const unsigned* __restrict__ sV, int m,
                          float c, int rev, int o) {
  int lo = o - m; if (lo < 0) lo = 0;
  int hi = o < n ? o : n;
  while (lo < hi) {
    int mid = (lo + hi + 1) >> 1;
    if (decodeU(U[mid - 1]) <= scaledAt(sV, m, o - mid, c, rev)) lo = mid;
    else hi = mid - 1;
  }
  return lo;
}

// One thread per merge-path boundary; all searches run with full TLP.
// A-merge: pX_k with c*sy (diagY); B-merge: pY_k with c*sx (diagX).
__global__ void k_splits(const unsigned* __restrict__ pX, const unsigned* __restrict__ pY,
                         const unsigned* __restrict__ sx, const unsigned* __restrict__ sy,
                         int N, int M, int k0, int mB,
                         const float* __restrict__ tbl, int* __restrict__ splits) {
  int b = blockIdx.x * blockDim.x + threadIdx.x;
  if (b >= mB) return;
  int kl = blockIdx.y;
  int kc = gridDim.y;
  float c = tbl[256 + k0 + kl];
  int rev = c < 0.0f ? 1 : 0;
  int Stot = N + M;
  int o = b * MOUT; if (o > Stot) o = Stot;
  const unsigned* U1 = pX + (size_t)kl * N;
  const unsigned* U2 = pY + (size_t)kl * M;
  splits[(size_t)kl * mB + b] = mergeSplit(U1, N, sy, M, c, rev, o);
  splits[((size_t)kc + kl) * mB + b] = mergeSplit(U2, M, sx, N, c, rev, o);
}

// split within LDS float arrays: a = sArr[0..aCnt), b = sArr[aCnt..aCnt+bCnt)
__device__ __forceinline__ int ldsSplit(const float* __restrict__ sArr, int aCnt, int bCnt,
                                        int o) {
  int lo = o - bCnt; if (lo < 0) lo = 0;
  int hi = o < aCnt ? o : aCnt;
  while (lo < hi) {
    int mid = (lo + hi + 1) >> 1;
    if (sArr[mid - 1] <= sArr[aCnt + o - mid]) lo = mid;
    else hi = mid - 1;
  }
  return lo;
}

// Branchless 8-output merge: 8+8 candidates to registers, bitonic half-merge.
__device__ __forceinline__ void merge8(const float* __restrict__ sArr, int aCnt, int bCnt,
                                       int la, int lb, float* m) {
  const float FMAX = 3.402823466e38f;
  float a[8], b[8];
#pragma unroll
  for (int j = 0; j < 8; ++j) {
    a[j] = (la + j < aCnt) ? sArr[la + j] : FMAX;
    b[j] = (lb + j < bCnt) ? sArr[aCnt + lb + j] : FMAX;
  }
#pragma unroll
  for (int j = 0; j < 8; ++j) m[j] = fminf(a[j], b[7 - j]);
#pragma unroll
  for (int d = 4; d > 0; d >>= 1) {
#pragma unroll
    for (int i = 0; i < 8; ++i) {
      if ((i & d) == 0 && (i | d) < 8) {
        float lo = fminf(m[i], m[i | d]);
        float hi = fmaxf(m[i], m[i | d]);
        m[i] = lo; m[i | d] = hi;
      }
    }
  }
}

__global__ __launch_bounds__(MBLK) void k_merge(const unsigned* __restrict__ pX,
                                                const unsigned* __restrict__ pY,
                                                const unsigned* __restrict__ sx,
                                                const unsigned* __restrict__ sy,
                                                int N, int M, int k0,
                                                const float* __restrict__ tbl,
                                                const int* __restrict__ splits, int mB,
                                                double* __restrict__ part) {
  __shared__ float sA[MOUT];
  __shared__ float sB[MOUT];
  __shared__ float red[MBLK];
  int kl = blockIdx.y;
  int kc = gridDim.y;
  float c = tbl[256 + k0 + kl];
  int rev = c < 0.0f ? 1 : 0;
  int Stot = N + M;
  int o0 = blockIdx.x * MOUT;
  int outCnt = min(MOUT, Stot - o0);
  const unsigned* U1 = pX + (size_t)kl * N;
  const unsigned* U2 = pY + (size_t)kl * M;
  int tid = threadIdx.x;
  int aLo = splits[(size_t)kl * mB + blockIdx.x];
  int aHi = splits[(size_t)kl * mB + blockIdx.x + 1];
  int a2Lo = splits[((size_t)kc + kl) * mB + blockIdx.x];
  int a2Hi = splits[((size_t)kc + kl) * mB + blockIdx.x + 1];
  int aCnt = aHi - aLo;
  int bLo = o0 - aLo, bCnt = outCnt - aCnt;
  int a2Cnt = a2Hi - a2Lo;
  int b2Lo = o0 - a2Lo, b2Cnt = outCnt - a2Cnt;
  for (int i = tid; i < aCnt; i += MBLK) sA[i] = decodeU(U1[aLo + i]);
  for (int i = tid; i < bCnt; i += MBLK) {
    int j = bLo + i;
    sA[aCnt + i] = c * decodeU(sy[rev ? (M - 1 - j) : j]);
  }
  for (int i = tid; i < a2Cnt; i += MBLK) sB[i] = decodeU(U2[a2Lo + i]);
  for (int i = tid; i < b2Cnt; i += MBLK) {
    int j = b2Lo + i;
    sB[a2Cnt + i] = c * decodeU(sx[rev ? (N - 1 - j) : j]);
  }
  __syncthreads();
  float acc = 0.0f;
#pragma unroll
  for (int half = 0; half < 2; ++half) {
    int lo0 = tid * MPT2 + half * 8;
    if (lo0 < outCnt) {
      int cnt = min(8, outCnt - lo0);
      int la = ldsSplit(sA, aCnt, bCnt, lo0);
      int lb = lo0 - la;
      int la2 = ldsSplit(sB, a2Cnt, b2Cnt, lo0);
      int lb2 = lo0 - la2;
      float mA[8], mB2[8];
      merge8(sA, aCnt, bCnt, la, lb, mA);
      merge8(sB, a2Cnt, b2Cnt, la2, lb2, mB2);
#pragma unroll
      for (int j = 0; j < 8; ++j)
        if (j < cnt) acc += fabsf(mA[j] - mB2[j]);
    }
  }
  red[tid] = acc;
  __syncthreads();
  for (int ofs = MBLK / 2; ofs > 0; ofs >>= 1) {
    if (tid < ofs) red[tid] += red[tid + ofs];
    __syncthreads();
  }
  if (tid == 0) {
    size_t slot = (size_t)(k0 + kl) * gridDim.x + blockIdx.x;
    part[slot] += (double)red[0];   // unique slot per block per dispatch; no atomics
  }
}

__global__ __launch_bounds__(256) void k_final(const double* __restrict__ part, int nSlots,
                                               float* __restrict__ out) {
  __shared__ double red[256];
  int tid = threadIdx.x;
  double s = 0.0;
  for (int i = tid; i < nSlots; i += 256) s += part[i];
  red[tid] = s;
  __syncthreads();
  for (int ofs = 128; ofs > 0; ofs >>= 1) {
    if (tid < ofs) red[tid] += red[tid + ofs];
    __syncthreads();
  }
  if (tid == 0) out[0] = (float)(red[0] / (double)KDIR);
}

extern "C" void kernel_launch(void* const* d_in, const int* in_sizes, int n_in,
                              void* d_out, int out_size, void* d_ws, size_t ws_size,
                              hipStream_t stream) {
  const float* X = (const float*)d_in[0];
  const float* Y = (const float*)d_in[1];
  int N = in_sizes[0] / 2;
  int M = in_sizes[1] / 2;

  char* ws = (char*)d_ws;
  size_t off = 0;
  auto alloc = [&](size_t b) -> void* {
    void* p = ws + off;
    off += (b + 255) & ~(size_t)255;
    return p;
  };
  float* tbl = (float*)alloc(512 * sizeof(float));
  unsigned* sPing = (unsigned*)alloc((size_t)(N + M) * 4);
  unsigned* sPong = (unsigned*)alloc((size_t)(N + M) * 4);

  int Tn = (N + TILE - 1) / TILE;
  int Tm = (M + TILE - 1) / TILE;
  int Tmax = Tn > Tm ? Tn : Tm;
  int mx = N > M ? N : M;
  int mBlocksAll = (N + M + MOUT - 1) / MOUT;
  int mB = mBlocksAll + 1;
  int nSlots = KDIR * mBlocksAll;
  int* splits = (int*)alloc((size_t)2 * KDIR * mB * 4);
  double* part = (double*)alloc((size_t)nSlots * 8);

  // per direction: ping+pong keys (2 segs) + counts (2 segs x 256 x Tmax);
  // reserve 2 extra segment rows (fused diagonal sort).
  size_t perDir = (size_t)(N + M) * 8 + (size_t)2 * 256 * Tmax * 4;
  size_t reserve = (size_t)2 * mx * 8 + (size_t)2 * 256 * Tmax * 4;
  size_t remain = ws_size > off ? ws_size - off : 0;
  remain = remain > reserve ? remain - reserve : 0;
  int Kc = (int)(remain / perDir);
  if (Kc > KDIR) Kc = KDIR;
  if (Kc < 1) Kc = 1;
  int maxSegs = 2 * Kc + 2;
  unsigned* counts8 = (unsigned*)alloc((size_t)maxSegs * 256 * Tmax * 4);
  unsigned* cPing = (unsigned*)alloc(((size_t)Kc * (N + M) + 2 * (size_t)mx) * 4);
  unsigned* cPong = (unsigned*)alloc(((size_t)Kc * (N + M) + 2 * (size_t)mx) * 4);

  k_table<<<1, 256, 0, stream>>>(tbl, part, nSlots);

  auto sortJob = [&](unsigned* ping, unsigned* pong, int segs, int L) {
    int T = (L + TILE - 1) / TILE;
    unsigned* s = pong;
    unsigned* d = ping;
    for (int p = 0; p < NPASS; ++p) {
      int shift = 8 * (p + 1);
      if (p > 0)
        k_hist8<<<dim3(T, segs), 256, 0, stream>>>(s, L, T, shift, counts8);
      k_scanSeg<<<segs, 256, 0, stream>>>(counts8, T);
      k_scatter8<<<dim3(T, segs), 256, 0, stream>>>(s, d, L, T, shift, counts8);
      unsigned* t = s; s = d; d = t;
    }
  };

  bool fused = (N == M) && (Kc == KDIR);

  if (fused) {
    unsigned* dXin = cPong + (size_t)2 * KDIR * N;
    unsigned* dYin = dXin + N;
    k_build<<<dim3(Tn, KDIR), 256, 0, stream>>>(X, N, 0, tbl, cPong, counts8, Tn, 0);
    k_build<<<dim3(Tn, KDIR), 256, 0, stream>>>(Y, N, 0, tbl, cPong + (size_t)KDIR * N,
                                                counts8, Tn, KDIR);
    k_build<<<dim3(Tn, 1), 256, 0, stream>>>(X, N, 100, tbl, dXin, counts8, Tn, 2 * KDIR);
    k_build<<<dim3(Tn, 1), 256, 0, stream>>>(Y, N, 100, tbl, dYin, counts8, Tn, 2 * KDIR + 1);
    sortJob(cPing, cPong, 2 * KDIR + 2, N);
    unsigned* pX = cPing;
    unsigned* pY = cPing + (size_t)KDIR * N;
    unsigned* dX = cPing + (size_t)2 * KDIR * N;
    unsigned* dY = dX + N;
    k_splits<<<dim3((mB + 255) / 256, KDIR), 256, 0, stream>>>(pX, pY, dX, dY, N, M, 0, mB,
                                                               tbl, splits);
    k_merge<<<dim3(mBlocksAll, KDIR), MBLK, 0, stream>>>(pX, pY, dX, dY, N, M, 0, tbl,
                                                         splits, mB, part);
  } else {
    // diagonal keys sorted separately (k=100 synthetic direction);
    // sPing[0,N) = sorted diagX, sPing+N [0,M) = sorted diagY.
    if (N == M) {
      k_build<<<dim3(Tn, 1), 256, 0, stream>>>(X, N, 100, tbl, sPong, counts8, Tn, 0);
      k_build<<<dim3(Tn, 1), 256, 0, stream>>>(Y, N, 100, tbl, sPong + N, counts8, Tn, 1);
      sortJob(sPing, sPong, 2, N);
    } else {
      k_build<<<dim3(Tn, 1), 256, 0, stream>>>(X, N, 100, tbl, sPong, counts8, Tn, 0);
      sortJob(sPing, sPong, 1, N);
      k_build<<<dim3(Tm, 1), 256, 0, stream>>>(Y, M, 100, tbl, sPong + N, counts8, Tm, 0);
      sortJob(sPing + N, sPong + N, 1, M);
    }
    for (int k0 = 0; k0 < KDIR; k0 += Kc) {
      int kc = (KDIR - k0 < Kc) ? (KDIR - k0) : Kc;
      unsigned* pXin = cPong;
      unsigned* pYin = cPong + (size_t)kc * N;
      unsigned* pX = cPing;
      unsigned* pY = cPing + (size_t)kc * N;
      if (N == M) {
        k_build<<<dim3(Tn, kc), 256, 0, stream>>>(X, N, k0, tbl, pXin, counts8, Tn, 0);
        k_build<<<dim3(Tn, kc), 256, 0, stream>>>(Y, N, k0, tbl, pYin, counts8, Tn, kc);
        sortJob(cPing, cPong, 2 * kc, N);
      } else {
        k_build<<<dim3(Tn, kc), 256, 0, stream>>>(X, N, k0, tbl, pXin, counts8, Tn, 0);
        sortJob(pX, pXin, kc, N);
        k_build<<<dim3(Tm, kc), 256, 0, stream>>>(Y, M, k0, tbl, pYin, counts8, Tm, 0);
        sortJob(pY, pYin, kc, M);
      }
      // sx = sorted diagX (sPing), sy = sorted diagY (sPing + N)
      k_splits<<<dim3((mB + 255) / 256, kc), 256, 0, stream>>>(pX, pY, sPing, sPing + N,
                                                               N, M, k0, mB, tbl, splits);
      k_merge<<<dim3(mBlocksAll, kc), MBLK, 0, stream>>>(pX, pY, sPing, sPing + N, N, M, k0,
                                                         tbl, splits, mB, part);
    }
  }
  k_final<<<1, 256, 0, stream>>>(part, nSlots, (float*)d_out);
}

// Round 15
// 950.681 us; speedup vs baseline: 1.0393x; 1.0393x over previous
//
#include <hip/hip_runtime.h>

#define KDIR 100
#define TILE 4096
#define NPASS 3
#define MBLK 512
#define MOUT 4096
#define MPT 8

__device__ __forceinline__ unsigned encodeF(float f) {
  unsigned u = __float_as_uint(f);
  return u ^ ((u >> 31) ? 0xFFFFFFFFu : 0x80000000u);
}
__device__ __forceinline__ float decodeU(unsigned u) {
  return __uint_as_float(u ^ ((u >> 31) ? 0x80000000u : 0xFFFFFFFFu));
}

// tbl layout: [0..99]=cos, [128..227]=sin, [256..355]=c=(cos+sin)*invn, [384..483]=invn
// synthetic entry k=100: (0.5, 0.5, invn=1) -> diagonal key 0.5*(x+y)
__global__ void k_table(float* tbl, double* part, int nSlots) {
  int k = threadIdx.x;
  const double PI = 3.14159265358979323846;
  if (k < KDIR) {
    double th = -PI * 0.5 + (double)k * (PI / (double)KDIR);
    float c = (float)cos(th), s = (float)sin(th);
    float invn = 1.0f / (c * c + s * s);
    tbl[k] = c; tbl[128 + k] = s; tbl[256 + k] = (c + s) * invn; tbl[384 + k] = invn;
  }
  if (k == 100) { tbl[100] = 0.5f; tbl[228] = 0.5f; tbl[484] = 1.0f; }
  for (int i = k; i < nSlots; i += 256) part[i] = 0.0;
}

// Fused projection-build + pass-0 (shift=8) per-tile histogram.
__global__ __launch_bounds__(256) void k_build(const float* __restrict__ P, int n, int kIdx,
                                               const float* __restrict__ tbl,
                                               unsigned* __restrict__ dst,
                                               unsigned* __restrict__ counts, int T, int seg0) {
  __shared__ unsigned h[256];
  int tid = threadIdx.x;
  h[tid] = 0;
  __syncthreads();
  int dir = blockIdx.y;
  int k = kIdx + dir;
  float ck = tbl[k], sk = tbl[128 + k], inv = tbl[384 + k];
  int tile = blockIdx.x;
  int start = tile * TILE;
  int nItems = min(TILE, n - start);
  unsigned* d0 = dst + (size_t)dir * n + start;
  const float* p0 = P + 2 * (size_t)start;
  if (nItems == TILE) {
    const float4* p4 = (const float4*)p0;
    uint2* o2 = (uint2*)d0;
#pragma unroll
    for (int i = 0; i < 8; ++i) {
      float4 v = p4[i * 256 + tid];
      unsigned ua = encodeF((v.x * ck + v.y * sk) * inv);
      unsigned ub = encodeF((v.z * ck + v.w * sk) * inv);
      o2[i * 256 + tid] = make_uint2(ua, ub);
      atomicAdd(&h[(ua >> 8) & 255u], 1u);
      atomicAdd(&h[(ub >> 8) & 255u], 1u);
    }
  } else {
    for (int j = tid; j < nItems; j += 256) {
      float x = p0[2 * j], y = p0[2 * j + 1];
      unsigned u = encodeF((x * ck + y * sk) * inv);
      d0[j] = u;
      atomicAdd(&h[(u >> 8) & 255u], 1u);
    }
  }
  __syncthreads();
  counts[((size_t)(seg0 + dir) * 256 + tid) * T + tile] = h[tid];
}

// Standalone per-pass histogram (non-fused fallback path only).
__global__ __launch_bounds__(256) void k_hist8(const unsigned* __restrict__ keys,
                                               int L, int T, int shift,
                                               unsigned* __restrict__ counts) {
  __shared__ unsigned h[4][256];
  int tid = threadIdx.x;
  int w = tid >> 6;
  for (int i = tid; i < 4 * 256; i += 256) ((unsigned*)h)[i] = 0;
  __syncthreads();
  int seg = blockIdx.y, tile = blockIdx.x;
  const unsigned* base = keys + (size_t)seg * L + (size_t)tile * TILE;
  int nItems = min(TILE, L - tile * TILE);
  if (nItems == TILE) {
    const uint4* b4 = (const uint4*)base;
#pragma unroll
    for (int i = 0; i < 4; ++i) {
      uint4 v = b4[i * 256 + tid];
      atomicAdd(&h[w][(v.x >> shift) & 255u], 1u);
      atomicAdd(&h[w][(v.y >> shift) & 255u], 1u);
      atomicAdd(&h[w][(v.z >> shift) & 255u], 1u);
      atomicAdd(&h[w][(v.w >> shift) & 255u], 1u);
    }
  } else {
    for (int i = tid; i < nItems; i += 256)
      atomicAdd(&h[w][(base[i] >> shift) & 255u], 1u);
  }
  __syncthreads();
  counts[((size_t)seg * 256 + tid) * T + tile] =
      h[0][tid] + h[1][tid] + h[2][tid] + h[3][tid];
}

// Per-segment exclusive scan of [256*T] (digit-major).
__global__ __launch_bounds__(256) void k_scanSeg(unsigned* __restrict__ counts, int T) {
  __shared__ unsigned tot[256];
  unsigned* c = counts + (size_t)blockIdx.x * 256 * T;
  int tid = threadIdx.x;
  int base = tid * T;
  unsigned sum = 0;
  for (int i = 0; i < T; ++i) sum += c[base + i];
  tot[tid] = sum;
  __syncthreads();
  for (int ofs = 1; ofs < 256; ofs <<= 1) {
    unsigned t = (tid >= ofs) ? tot[tid - ofs] : 0u;
    __syncthreads();
    tot[tid] += t;
    __syncthreads();
  }
  unsigned run = tot[tid] - sum;
  for (int i = 0; i < T; ++i) {
    unsigned v = c[base + i];
    c[base + i] = run;
    run += v;
  }
}

// 8-bit scatter, STABLE, two-phase. Optionally accumulates the NEXT pass's
// per-(dest-tile, digit2) histogram during the coalesced write (run-leader
// aggregated global atomics) -- eliminates the standalone hist kernel.
__global__ __launch_bounds__(256) void k_scatter8(const unsigned* __restrict__ src,
                                                  unsigned* __restrict__ dst,
                                                  int L, int T, int shift,
                                                  const unsigned* __restrict__ counts,
                                                  unsigned* __restrict__ nextCounts,
                                                  int shift2) {
  __shared__ unsigned runG[4][4][256];
  __shared__ unsigned diffD[256];
  __shared__ unsigned wsum[4];
  int tid = threadIdx.x;
  int lane = tid & 63, w = tid >> 6;
  int seg = blockIdx.y, tile = blockIdx.x;
  const unsigned* sbase = src + (size_t)seg * L + (size_t)tile * TILE;
  int nItems = min(TILE, L - tile * TILE);
  for (int i = tid; i < 4 * 4 * 256; i += 256) ((unsigned*)runG)[i] = 0;
  __syncthreads();
  unsigned kk[16];
  unsigned rr[16];
  unsigned long long laneLT = (1ull << lane) - 1ull;
  int jbase = w * (TILE / 4);
#pragma unroll
  for (int i = 0; i < 16; ++i) {
    int j = jbase + i * 64 + lane;
    kk[i] = (j < nItems) ? sbase[j] : 0xFFFFFFFFu;
  }
#pragma unroll
  for (int s = 0; s < 4; ++s) {
    unsigned long long mask[4];
    unsigned prev[4];
#pragma unroll
    for (int g = 0; g < 4; ++g) {
      int i = g * 4 + s;
      int j = jbase + i * 64 + lane;
      bool valid = j < nItems;
      unsigned long long act = __ballot(valid);
      unsigned d = (kk[i] >> shift) & 255u;
      unsigned long long m = act;
#pragma unroll
      for (int b = 0; b < 8; ++b) {
        unsigned long long bal = __ballot((d >> b) & 1);
        m &= ((d >> b) & 1) ? bal : ~bal;
      }
      mask[g] = m;
      prev[g] = runG[w][g][d];
    }
#pragma unroll
    for (int g = 0; g < 4; ++g) {
      int i = g * 4 + s;
      int j = jbase + i * 64 + lane;
      if (j < nItems) {
        unsigned d = (kk[i] >> shift) & 255u;
        unsigned r = (unsigned)__popcll(mask[g] & laneLT);
        rr[i] = prev[g] + r;
        if (r == 0) runG[w][g][d] = prev[g] + (unsigned)__popcll(mask[g]);
      }
    }
  }
  __syncthreads();
  {
    unsigned v[16];
#pragma unroll
    for (int w2 = 0; w2 < 4; ++w2)
#pragma unroll
      for (int g2 = 0; g2 < 4; ++g2) v[w2 * 4 + g2] = runG[w2][g2][tid];
    unsigned tot = 0;
#pragma unroll
    for (int i = 0; i < 16; ++i) {
      unsigned t = v[i];
      v[i] = tot;
      tot += t;
    }
    unsigned x = tot;
#pragma unroll
    for (int ofs = 1; ofs < 64; ofs <<= 1) {
      unsigned t = __shfl_up(x, ofs, 64);
      if (lane >= ofs) x += t;
    }
    if (lane == 63) wsum[w] = x;
    __syncthreads();
    unsigned basew = 0;
#pragma unroll
    for (int w2 = 0; w2 < 4; ++w2) basew += (w2 < w) ? wsum[w2] : 0u;
    unsigned localStart = basew + x - tot;
    diffD[tid] = counts[((size_t)seg * 256 + tid) * T + tile] - localStart;
#pragma unroll
    for (int w2 = 0; w2 < 4; ++w2)
#pragma unroll
      for (int g2 = 0; g2 < 4; ++g2)
        runG[w2][g2][tid] = v[w2 * 4 + g2] + localStart;
  }
  __syncthreads();
  unsigned lp[16];
#pragma unroll
  for (int i = 0; i < 16; ++i) {
    unsigned d = (kk[i] >> shift) & 255u;
    lp[i] = runG[w][i >> 2][d] + rr[i];
  }
  __syncthreads();
  unsigned* kbuf = &runG[0][0][0];
#pragma unroll
  for (int i = 0; i < 16; ++i) {
    int j = jbase + i * 64 + lane;
    if (j < nItems) kbuf[lp[i]] = kk[i];
  }
  __syncthreads();
  unsigned* dbase = dst + (size_t)seg * L;
#pragma unroll
  for (int i = 0; i < 16; ++i) {
    int pos = i * 256 + tid;
    bool valid = pos < nItems;
    unsigned k = 0, g = 0, d2 = 0;
    if (valid) {
      k = kbuf[pos];
      unsigned d = (k >> shift) & 255u;
      g = diffD[d] + (unsigned)pos;
      dbase[g] = k;
      d2 = (k >> shift2) & 255u;
    }
    if (nextCounts) {
      // run-leader aggregation over (destTile, d2); invalid lanes are a suffix
      unsigned pid = ((g >> 12) << 8) | d2;
      unsigned prevPid = __shfl_up(pid, 1, 64);
      bool leader = valid && (lane == 0 || pid != prevPid);
      unsigned long long lm = __ballot(leader);
      unsigned long long vm = __ballot(valid);
      unsigned long long bounds = lm | ~vm;
      unsigned long long above = bounds & ~((2ull << lane) - 1ull);
      if (leader) {
        int nxt = above ? __builtin_ctzll(above) : 64;
        unsigned cnt = (unsigned)(nxt - lane);
        atomicAdd(&nextCounts[((size_t)seg * 256 + d2) * T + (g >> 12)], cnt);
      }
    }
  }
}

__device__ __forceinline__ float scaledAt(const unsigned* __restrict__ s, int len, int j,
                                          float c, int rev) {
  return c * decodeU(s[rev ? (len - 1 - j) : j]);
}

__device__ int mergeSplit(const unsigned* __restrict__ U, int n,
                          const unsigned* __restrict__ sV, int m,
                          float c, int rev, int o) {
  int lo = o - m; if (lo < 0) lo = 0;
  int hi = o < n ? o : n;
  while (lo < hi) {
    int mid = (lo + hi + 1) >> 1;
    if (decodeU(U[mid - 1]) <= scaledAt(sV, m, o - mid, c, rev)) lo = mid;
    else hi = mid - 1;
  }
  return lo;
}

// One thread per merge-path boundary; full TLP.
__global__ void k_splits(const unsigned* __restrict__ pX, const unsigned* __restrict__ pY,
                         const unsigned* __restrict__ sx, const unsigned* __restrict__ sy,
                         int N, int M, int k0, int mB,
                         const float* __restrict__ tbl, int* __restrict__ splits) {
  int b = blockIdx.x * blockDim.x + threadIdx.x;
  if (b >= mB) return;
  int kl = blockIdx.y;
  int kc = gridDim.y;
  float c = tbl[256 + k0 + kl];
  int rev = c < 0.0f ? 1 : 0;
  int Stot = N + M;
  int o = b * MOUT; if (o > Stot) o = Stot;
  const unsigned* U1 = pX + (size_t)kl * N;
  const unsigned* U2 = pY + (size_t)kl * M;
  splits[(size_t)kl * mB + b] = mergeSplit(U1, N, sy, M, c, rev, o);
  splits[((size_t)kc + kl) * mB + b] = mergeSplit(U2, M, sx, N, c, rev, o);
}

__device__ __forceinline__ int ldsSplit(const float* __restrict__ sArr, int aCnt, int bCnt,
                                        int o) {
  int lo = o - bCnt; if (lo < 0) lo = 0;
  int hi = o < aCnt ? o : aCnt;
  while (lo < hi) {
    int mid = (lo + hi + 1) >> 1;
    if (sArr[mid - 1] <= sArr[aCnt + o - mid]) lo = mid;
    else hi = mid - 1;
  }
  return lo;
}

// Branchless 8-output merge via bitonic half-merge.
__device__ __forceinline__ void merge8(const float* __restrict__ sArr, int aCnt, int bCnt,
                                       int la, int lb, float* m) {
  const float FMAX = 3.402823466e38f;
  float a[8], b[8];
#pragma unroll
  for (int j = 0; j < 8; ++j) {
    a[j] = (la + j < aCnt) ? sArr[la + j] : FMAX;
    b[j] = (lb + j < bCnt) ? sArr[aCnt + lb + j] : FMAX;
  }
#pragma unroll
  for (int j = 0; j < 8; ++j) m[j] = fminf(a[j], b[7 - j]);
#pragma unroll
  for (int d = 4; d > 0; d >>= 1) {
#pragma unroll
    for (int i = 0; i < 8; ++i) {
      if ((i & d) == 0 && (i | d) < 8) {
        float lo = fminf(m[i], m[i | d]);
        float hi = fmaxf(m[i], m[i | d]);
        m[i] = lo; m[i | d] = hi;
      }
    }
  }
}

__global__ __launch_bounds__(MBLK) void k_merge(const unsigned* __restrict__ pX,
                                                const unsigned* __restrict__ pY,
                                                const unsigned* __restrict__ sx,
                                                const unsigned* __restrict__ sy,
                                                int N, int M, int k0,
                                                const float* __restrict__ tbl,
                                                const int* __restrict__ splits, int mB,
                                                double* __restrict__ part) {
  __shared__ float sA[MOUT];
  __shared__ float sB[MOUT];
  __shared__ float red[MBLK];
  int kl = blockIdx.y;
  int kc = gridDim.y;
  float c = tbl[256 + k0 + kl];
  int rev = c < 0.0f ? 1 : 0;
  int Stot = N + M;
  int o0 = blockIdx.x * MOUT;
  int outCnt = min(MOUT, Stot - o0);
  const unsigned* U1 = pX + (size_t)kl * N;
  const unsigned* U2 = pY + (size_t)kl * M;
  int tid = threadIdx.x;
  int aLo = splits[(size_t)kl * mB + blockIdx.x];
  int aHi = splits[(size_t)kl * mB + blockIdx.x + 1];
  int a2Lo = splits[((size_t)kc + kl) * mB + blockIdx.x];
  int a2Hi = splits[((size_t)kc + kl) * mB + blockIdx.x + 1];
  int aCnt = aHi - aLo;
  int bLo = o0 - aLo, bCnt = outCnt - aCnt;
  int a2Cnt = a2Hi - a2Lo;
  int b2Lo = o0 - a2Lo, b2Cnt = outCnt - a2Cnt;
  for (int i = tid; i < aCnt; i += MBLK) sA[i] = decodeU(U1[aLo + i]);
  for (int i = tid; i < bCnt; i += MBLK) {
    int j = bLo + i;
    sA[aCnt + i] = c * decodeU(sy[rev ? (M - 1 - j) : j]);
  }
  for (int i = tid; i < a2Cnt; i += MBLK) sB[i] = decodeU(U2[a2Lo + i]);
  for (int i = tid; i < b2Cnt; i += MBLK) {
    int j = b2Lo + i;
    sB[a2Cnt + i] = c * decodeU(sx[rev ? (N - 1 - j) : j]);
  }
  __syncthreads();
  float acc = 0.0f;
  int lo0 = tid * MPT;
  if (lo0 < outCnt) {
    int cnt = min(MPT, outCnt - lo0);
    int la = ldsSplit(sA, aCnt, bCnt, lo0);
    int lb = lo0 - la;
    int la2 = ldsSplit(sB, a2Cnt, b2Cnt, lo0);
    int lb2 = lo0 - la2;
    float mA[8], mB2[8];
    merge8(sA, aCnt, bCnt, la, lb, mA);
    merge8(sB, a2Cnt, b2Cnt, la2, lb2, mB2);
#pragma unroll
    for (int j = 0; j < 8; ++j)
      if (j < cnt) acc += fabsf(mA[j] - mB2[j]);
  }
  red[tid] = acc;
  __syncthreads();
  for (int ofs = MBLK / 2; ofs > 0; ofs >>= 1) {
    if (tid < ofs) red[tid] += red[tid + ofs];
    __syncthreads();
  }
  if (tid == 0) {
    size_t slot = (size_t)(k0 + kl) * gridDim.x + blockIdx.x;
    part[slot] += (double)red[0];
  }
}

__global__ __launch_bounds__(256) void k_final(const double* __restrict__ part, int nSlots,
                                               float* __restrict__ out) {
  __shared__ double red[256];
  int tid = threadIdx.x;
  double s = 0.0;
  for (int i = tid; i < nSlots; i += 256) s += part[i];
  red[tid] = s;
  __syncthreads();
  for (int ofs = 128; ofs > 0; ofs >>= 1) {
    if (tid < ofs) red[tid] += red[tid + ofs];
    __syncthreads();
  }
  if (tid == 0) out[0] = (float)(red[0] / (double)KDIR);
}

extern "C" void kernel_launch(void* const* d_in, const int* in_sizes, int n_in,
                              void* d_out, int out_size, void* d_ws, size_t ws_size,
                              hipStream_t stream) {
  const float* X = (const float*)d_in[0];
  const float* Y = (const float*)d_in[1];
  int N = in_sizes[0] / 2;
  int M = in_sizes[1] / 2;

  char* ws = (char*)d_ws;
  size_t off = 0;
  auto alloc = [&](size_t b) -> void* {
    void* p = ws + off;
    off += (b + 255) & ~(size_t)255;
    return p;
  };
  float* tbl = (float*)alloc(512 * sizeof(float));
  unsigned* sPing = (unsigned*)alloc((size_t)(N + M) * 4);
  unsigned* sPong = (unsigned*)alloc((size_t)(N + M) * 4);

  int Tn = (N + TILE - 1) / TILE;
  int Tm = (M + TILE - 1) / TILE;
  int Tmax = Tn > Tm ? Tn : Tm;
  int mx = N > M ? N : M;
  int mBlocksAll = (N + M + MOUT - 1) / MOUT;
  int mB = mBlocksAll + 1;
  int nSlots = KDIR * mBlocksAll;
  int* splits = (int*)alloc((size_t)2 * KDIR * mB * 4);
  double* part = (double*)alloc((size_t)nSlots * 8);

  // per direction: ping+pong keys (2 segs) + two counts buffers
  size_t perDir = (size_t)(N + M) * 8 + (size_t)4 * 256 * Tmax * 4;
  size_t reserve = (size_t)2 * mx * 8 + (size_t)4 * 256 * Tmax * 4;
  size_t remain = ws_size > off ? ws_size - off : 0;
  remain = remain > reserve ? remain - reserve : 0;
  int Kc = (int)(remain / perDir);
  if (Kc > KDIR) Kc = KDIR;
  if (Kc < 1) Kc = 1;
  int maxSegs = 2 * Kc + 2;
  size_t cntElems = (size_t)maxSegs * 256 * Tmax;
  unsigned* countsA = (unsigned*)alloc(cntElems * 4);
  unsigned* countsB = (unsigned*)alloc(cntElems * 4);
  unsigned* cPing = (unsigned*)alloc(((size_t)Kc * (N + M) + 2 * (size_t)mx) * 4);
  unsigned* cPong = (unsigned*)alloc(((size_t)Kc * (N + M) + 2 * (size_t)mx) * 4);

  k_table<<<1, 256, 0, stream>>>(tbl, part, nSlots);

  // non-fused fallback: classic hist+scan+scatter, single counts buffer
  auto sortJob = [&](unsigned* ping, unsigned* pong, int segs, int L) {
    int T = (L + TILE - 1) / TILE;
    unsigned* s = pong;
    unsigned* d = ping;
    for (int p = 0; p < NPASS; ++p) {
      int shift = 8 * (p + 1);
      if (p > 0)
        k_hist8<<<dim3(T, segs), 256, 0, stream>>>(s, L, T, shift, countsA);
      k_scanSeg<<<segs, 256, 0, stream>>>(countsA, T);
      k_scatter8<<<dim3(T, segs), 256, 0, stream>>>(s, d, L, T, shift, countsA,
                                                    (unsigned*)nullptr, 0);
      unsigned* t = s; s = d; d = t;
    }
  };

  bool fused = (N == M) && (Kc == KDIR);

  if (fused) {
    unsigned* dXin = cPong + (size_t)2 * KDIR * N;
    unsigned* dYin = dXin + N;
    k_build<<<dim3(Tn, KDIR), 256, 0, stream>>>(X, N, 0, tbl, cPong, countsA, Tn, 0);
    k_build<<<dim3(Tn, KDIR), 256, 0, stream>>>(Y, N, 0, tbl, cPong + (size_t)KDIR * N,
                                                countsA, Tn, KDIR);
    k_build<<<dim3(Tn, 1), 256, 0, stream>>>(X, N, 100, tbl, dXin, countsA, Tn, 2 * KDIR);
    k_build<<<dim3(Tn, 1), 256, 0, stream>>>(Y, N, 100, tbl, dYin, countsA, Tn, 2 * KDIR + 1);
    int segs = 2 * KDIR + 2;
    int T = Tn;
    size_t cntBytes = (size_t)segs * 256 * T * 4;
    // pass 0: pong -> ping (shift 8), accumulate pass-1 hist into countsB
    hipMemsetAsync(countsB, 0, cntBytes, stream);
    k_scanSeg<<<segs, 256, 0, stream>>>(countsA, T);
    k_scatter8<<<dim3(T, segs), 256, 0, stream>>>(cPong, cPing, N, T, 8, countsA,
                                                  countsB, 16);
    // pass 1: ping -> pong (shift 16), accumulate pass-2 hist into countsA
    k_scanSeg<<<segs, 256, 0, stream>>>(countsB, T);
    hipMemsetAsync(countsA, 0, cntBytes, stream);
    k_scatter8<<<dim3(T, segs), 256, 0, stream>>>(cPing, cPong, N, T, 16, countsB,
                                                  countsA, 24);
    // pass 2: pong -> ping (shift 24), no next hist
    k_scanSeg<<<segs, 256, 0, stream>>>(countsA, T);
    k_scatter8<<<dim3(T, segs), 256, 0, stream>>>(cPong, cPing, N, T, 24, countsA,
                                                  (unsigned*)nullptr, 0);
    unsigned* pX = cPing;
    unsigned* pY = cPing + (size_t)KDIR * N;
    unsigned* dX = cPing + (size_t)2 * KDIR * N;
    unsigned* dY = dX + N;
    k_splits<<<dim3((mB + 255) / 256, KDIR), 256, 0, stream>>>(pX, pY, dX, dY, N, M, 0, mB,
                                                               tbl, splits);
    k_merge<<<dim3(mBlocksAll, KDIR), MBLK, 0, stream>>>(pX, pY, dX, dY, N, M, 0, tbl,
                                                         splits, mB, part);
  } else {
    // diagonal keys sorted separately (k=100 synthetic direction);
    // sPing[0,N) = sorted diagX, sPing+N [0,M) = sorted diagY.
    if (N == M) {
      k_build<<<dim3(Tn, 1), 256, 0, stream>>>(X, N, 100, tbl, sPong, countsA, Tn, 0);
      k_build<<<dim3(Tn, 1), 256, 0, stream>>>(Y, N, 100, tbl, sPong + N, countsA, Tn, 1);
      sortJob(sPing, sPong, 2, N);
    } else {
      k_build<<<dim3(Tn, 1), 256, 0, stream>>>(X, N, 100, tbl, sPong, countsA, Tn, 0);
      sortJob(sPing, sPong, 1, N);
      k_build<<<dim3(Tm, 1), 256, 0, stream>>>(Y, M, 100, tbl, sPong + N, countsA, Tm, 0);
      sortJob(sPing + N, sPong + N, 1, M);
    }
    for (int k0 = 0; k0 < KDIR; k0 += Kc) {
      int kc = (KDIR - k0 < Kc) ? (KDIR - k0) : Kc;
      unsigned* pXin = cPong;
      unsigned* pYin = cPong + (size_t)kc * N;
      unsigned* pX = cPing;
      unsigned* pY = cPing + (size_t)kc * N;
      if (N == M) {
        k_build<<<dim3(Tn, kc), 256, 0, stream>>>(X, N, k0, tbl, pXin, countsA, Tn, 0);
        k_build<<<dim3(Tn, kc), 256, 0, stream>>>(Y, N, k0, tbl, pYin, countsA, Tn, kc);
        sortJob(cPing, cPong, 2 * kc, N);
      } else {
        k_build<<<dim3(Tn, kc), 256, 0, stream>>>(X, N, k0, tbl, pXin, countsA, Tn, 0);
        sortJob(pX, pXin, kc, N);
        k_build<<<dim3(Tm, kc), 256, 0, stream>>>(Y, M, k0, tbl, pYin, countsA, Tm, 0);
        sortJob(pY, pYin, kc, M);
      }
      k_splits<<<dim3((mB + 255) / 256, kc), 256, 0, stream>>>(pX, pY, sPing, sPing + N,
                                                               N, M, k0, mB, tbl, splits);
      k_merge<<<dim3(mBlocksAll, kc), MBLK, 0, stream>>>(pX, pY, sPing, sPing + N, N, M, k0,
                                                         tbl, splits, mB, part);
    }
  }
  k_final<<<1, 256, 0, stream>>>(part, nSlots, (float*)d_out);
}

// Round 16
// 911.876 us; speedup vs baseline: 1.0836x; 1.0426x over previous
//
#include <hip/hip_runtime.h>

#define KDIR 100
#define TILE 4096
#define NPASS 3
#define MBLK 512
#define MOUT 4096
#define MPT 8

struct TrueT  { static constexpr bool value = true; };
struct FalseT { static constexpr bool value = false; };

__device__ __forceinline__ unsigned encodeF(float f) {
  unsigned u = __float_as_uint(f);
  return u ^ ((u >> 31) ? 0xFFFFFFFFu : 0x80000000u);
}
__device__ __forceinline__ float decodeU(unsigned u) {
  return __uint_as_float(u ^ ((u >> 31) ? 0x80000000u : 0xFFFFFFFFu));
}

// tbl layout: [0..99]=cos, [128..227]=sin, [256..355]=c=(cos+sin)*invn, [384..483]=invn
// synthetic entry k=100: (0.5, 0.5, invn=1) -> diagonal key 0.5*(x+y)
__global__ void k_table(float* tbl, double* part, int nSlots) {
  int k = threadIdx.x;
  const double PI = 3.14159265358979323846;
  if (k < KDIR) {
    double th = -PI * 0.5 + (double)k * (PI / (double)KDIR);
    float c = (float)cos(th), s = (float)sin(th);
    float invn = 1.0f / (c * c + s * s);
    tbl[k] = c; tbl[128 + k] = s; tbl[256 + k] = (c + s) * invn; tbl[384 + k] = invn;
  }
  if (k == 100) { tbl[100] = 0.5f; tbl[228] = 0.5f; tbl[484] = 1.0f; }
  for (int i = k; i < nSlots; i += 256) part[i] = 0.0;
}

__device__ __forceinline__ void buildTile(const float* __restrict__ p0, int nItems,
                                          float ck, float sk, float inv,
                                          unsigned* __restrict__ d0, unsigned* h, int tid) {
  if (nItems == TILE) {
    const float4* p4 = (const float4*)p0;
    uint2* o2 = (uint2*)d0;
#pragma unroll
    for (int i = 0; i < 8; ++i) {
      float4 v = p4[i * 256 + tid];
      unsigned ua = encodeF((v.x * ck + v.y * sk) * inv);
      unsigned ub = encodeF((v.z * ck + v.w * sk) * inv);
      o2[i * 256 + tid] = make_uint2(ua, ub);
      atomicAdd(&h[(ua >> 8) & 255u], 1u);
      atomicAdd(&h[(ub >> 8) & 255u], 1u);
    }
  } else {
    for (int j = tid; j < nItems; j += 256) {
      float x = p0[2 * j], y = p0[2 * j + 1];
      unsigned u = encodeF((x * ck + y * sk) * inv);
      d0[j] = u;
      atomicAdd(&h[(u >> 8) & 255u], 1u);
    }
  }
}

// Fused projection-build + pass-0 hist for ALL 202 segments (fused path).
// dir<100: X dirs; 100..199: Y dirs; 200: diagX; 201: diagY. out = dst + dir*N.
__global__ __launch_bounds__(256) void k_buildAll(const float* __restrict__ X,
                                                  const float* __restrict__ Y, int n,
                                                  const float* __restrict__ tbl,
                                                  unsigned* __restrict__ dst,
                                                  unsigned* __restrict__ counts, int T) {
  __shared__ unsigned h[256];
  int tid = threadIdx.x;
  h[tid] = 0;
  __syncthreads();
  int dir = blockIdx.y;
  int k = (dir < KDIR) ? dir : (dir < 2 * KDIR ? dir - KDIR : KDIR);
  const float* P = (dir < KDIR || dir == 2 * KDIR) ? X : Y;
  float ck = tbl[k], sk = tbl[128 + k], inv = tbl[384 + k];
  int tile = blockIdx.x;
  int start = tile * TILE;
  int nItems = min(TILE, n - start);
  buildTile(P + 2 * (size_t)start, nItems, ck, sk, inv,
            dst + (size_t)dir * n + start, h, tid);
  __syncthreads();
  counts[((size_t)dir * 256 + tid) * T + tile] = h[tid];
}

// Single-source build (non-fused fallback path).
__global__ __launch_bounds__(256) void k_build(const float* __restrict__ P, int n, int kIdx,
                                               const float* __restrict__ tbl,
                                               unsigned* __restrict__ dst,
                                               unsigned* __restrict__ counts, int T, int seg0) {
  __shared__ unsigned h[256];
  int tid = threadIdx.x;
  h[tid] = 0;
  __syncthreads();
  int dir = blockIdx.y;
  int k = kIdx + dir;
  float ck = tbl[k], sk = tbl[128 + k], inv = tbl[384 + k];
  int tile = blockIdx.x;
  int start = tile * TILE;
  int nItems = min(TILE, n - start);
  buildTile(P + 2 * (size_t)start, nItems, ck, sk, inv,
            dst + (size_t)dir * n + start, h, tid);
  __syncthreads();
  counts[((size_t)(seg0 + dir) * 256 + tid) * T + tile] = h[tid];
}

// Standalone per-pass histogram (non-fused fallback path only).
__global__ __launch_bounds__(256) void k_hist8(const unsigned* __restrict__ keys,
                                               int L, int T, int shift,
                                               unsigned* __restrict__ counts) {
  __shared__ unsigned h[4][256];
  int tid = threadIdx.x;
  int w = tid >> 6;
  for (int i = tid; i < 4 * 256; i += 256) ((unsigned*)h)[i] = 0;
  __syncthreads();
  int seg = blockIdx.y, tile = blockIdx.x;
  const unsigned* base = keys + (size_t)seg * L + (size_t)tile * TILE;
  int nItems = min(TILE, L - tile * TILE);
  if (nItems == TILE) {
    const uint4* b4 = (const uint4*)base;
#pragma unroll
    for (int i = 0; i < 4; ++i) {
      uint4 v = b4[i * 256 + tid];
      atomicAdd(&h[w][(v.x >> shift) & 255u], 1u);
      atomicAdd(&h[w][(v.y >> shift) & 255u], 1u);
      atomicAdd(&h[w][(v.z >> shift) & 255u], 1u);
      atomicAdd(&h[w][(v.w >> shift) & 255u], 1u);
    }
  } else {
    for (int i = tid; i < nItems; i += 256)
      atomicAdd(&h[w][(base[i] >> shift) & 255u], 1u);
  }
  __syncthreads();
  counts[((size_t)seg * 256 + tid) * T + tile] =
      h[0][tid] + h[1][tid] + h[2][tid] + h[3][tid];
}

// Per-segment exclusive scan of [256*T] (digit-major).
__global__ __launch_bounds__(256) void k_scanSeg(unsigned* __restrict__ counts, int T) {
  __shared__ unsigned tot[256];
  unsigned* c = counts + (size_t)blockIdx.x * 256 * T;
  int tid = threadIdx.x;
  int base = tid * T;
  unsigned sum = 0;
  for (int i = 0; i < T; ++i) sum += c[base + i];
  tot[tid] = sum;
  __syncthreads();
  for (int ofs = 1; ofs < 256; ofs <<= 1) {
    unsigned t = (tid >= ofs) ? tot[tid - ofs] : 0u;
    __syncthreads();
    tot[tid] += t;
    __syncthreads();
  }
  unsigned run = tot[tid] - sum;
  for (int i = 0; i < T; ++i) {
    unsigned v = c[base + i];
    c[base + i] = run;
    run += v;
  }
}

// 8-bit scatter, STABLE, two-phase, full-tile specialized.
__global__ __launch_bounds__(256) void k_scatter8(const unsigned* __restrict__ src,
                                                  unsigned* __restrict__ dst,
                                                  int L, int T, int shift,
                                                  const unsigned* __restrict__ counts,
                                                  unsigned* __restrict__ nextCounts,
                                                  int shift2) {
  __shared__ unsigned runG[4][4][256];
  __shared__ unsigned diffD[256];
  __shared__ unsigned wsum[4];
  int tid = threadIdx.x;
  int lane = tid & 63, w = tid >> 6;
  int seg = blockIdx.y, tile = blockIdx.x;
  const unsigned* sbase = src + (size_t)seg * L + (size_t)tile * TILE;
  int nItems = min(TILE, L - tile * TILE);
  for (int i = tid; i < 4 * 4 * 256; i += 256) ((unsigned*)runG)[i] = 0;
  __syncthreads();
  unsigned kk[16];
  unsigned rr[16];
  unsigned long long laneLT = (1ull << lane) - 1ull;
  unsigned long long aboveM = ~((laneLT << 1) | 1ull);  // lanes strictly above
  int jbase = w * (TILE / 4);

  auto body = [&](auto FULLC) {
    constexpr bool FULL = decltype(FULLC)::value;
    // load
#pragma unroll
    for (int i = 0; i < 16; ++i) {
      int j = jbase + i * 64 + lane;
      kk[i] = (FULL || j < nItems) ? sbase[j] : 0xFFFFFFFFu;
    }
    // ranking
#pragma unroll
    for (int s = 0; s < 4; ++s) {
      unsigned long long mask[4];
      unsigned prev[4];
#pragma unroll
      for (int g = 0; g < 4; ++g) {
        int i = g * 4 + s;
        unsigned d = (kk[i] >> shift) & 255u;
        unsigned long long m = FULL ? ~0ull : __ballot(jbase + i * 64 + lane < nItems);
#pragma unroll
        for (int b = 0; b < 8; ++b) {
          unsigned long long bal = __ballot((d >> b) & 1);
          m &= ((d >> b) & 1) ? bal : ~bal;
        }
        mask[g] = m;
        prev[g] = runG[w][g][d];
      }
#pragma unroll
      for (int g = 0; g < 4; ++g) {
        int i = g * 4 + s;
        if (FULL || jbase + i * 64 + lane < nItems) {
          unsigned d = (kk[i] >> shift) & 255u;
          unsigned r = (unsigned)__popcll(mask[g] & laneLT);
          rr[i] = prev[g] + r;
          if (r == 0) runG[w][g][d] = prev[g] + (unsigned)__popcll(mask[g]);
        }
      }
    }
    __syncthreads();
    // register-resident fold: tid == digit
    {
      unsigned v[16];
#pragma unroll
      for (int w2 = 0; w2 < 4; ++w2)
#pragma unroll
        for (int g2 = 0; g2 < 4; ++g2) v[w2 * 4 + g2] = runG[w2][g2][tid];
      unsigned tot = 0;
#pragma unroll
      for (int i = 0; i < 16; ++i) {
        unsigned t = v[i];
        v[i] = tot;
        tot += t;
      }
      unsigned x = tot;
#pragma unroll
      for (int ofs = 1; ofs < 64; ofs <<= 1) {
        unsigned t = __shfl_up(x, ofs, 64);
        if (lane >= ofs) x += t;
      }
      if (lane == 63) wsum[w] = x;
      __syncthreads();
      unsigned basew = 0;
#pragma unroll
      for (int w2 = 0; w2 < 4; ++w2) basew += (w2 < w) ? wsum[w2] : 0u;
      unsigned localStart = basew + x - tot;
      diffD[tid] = counts[((size_t)seg * 256 + tid) * T + tile] - localStart;
#pragma unroll
      for (int w2 = 0; w2 < 4; ++w2)
#pragma unroll
        for (int g2 = 0; g2 < 4; ++g2)
          runG[w2][g2][tid] = v[w2 * 4 + g2] + localStart;
    }
    __syncthreads();
    unsigned lp[16];
#pragma unroll
    for (int i = 0; i < 16; ++i) {
      unsigned d = (kk[i] >> shift) & 255u;
      lp[i] = runG[w][i >> 2][d] + rr[i];
    }
    __syncthreads();
    unsigned* kbuf = &runG[0][0][0];
#pragma unroll
    for (int i = 0; i < 16; ++i) {
      if (FULL || jbase + i * 64 + lane < nItems) kbuf[lp[i]] = kk[i];
    }
    __syncthreads();
    unsigned* dbase = dst + (size_t)seg * L;
#pragma unroll
    for (int i = 0; i < 16; ++i) {
      int pos = i * 256 + tid;
      bool valid = FULL || pos < nItems;
      unsigned k = 0, g = 0, d2 = 0;
      if (valid) {
        k = kbuf[pos];
        unsigned d = (k >> shift) & 255u;
        g = diffD[d] + (unsigned)pos;
        dbase[g] = k;
        d2 = (k >> shift2) & 255u;
      }
      if (nextCounts) {
        unsigned pid = ((g >> 12) << 8) | d2;
        unsigned prevPid = __shfl_up(pid, 1, 64);
        bool leader = valid && (lane == 0 || pid != prevPid);
        unsigned long long lm = __ballot(leader);
        unsigned long long bounds;
        if (FULL) bounds = lm;
        else bounds = lm | ~__ballot(valid);
        if (leader) {
          unsigned long long above = bounds & aboveM;
          int nxt = above ? __builtin_ctzll(above) : 64;
          atomicAdd(&nextCounts[((size_t)seg * 256 + d2) * T + (g >> 12)],
                    (unsigned)(nxt - lane));
        }
      }
    }
  };
  if (nItems == TILE) body(TrueT{});
  else body(FalseT{});
}

__device__ __forceinline__ float scaledAt(const unsigned* __restrict__ s, int len, int j,
                                          float c, int rev) {
  return c * decodeU(s[rev ? (len - 1 - j) : j]);
}

__device__ int mergeSplit(const unsigned* __restrict__ U, int n,
                          const unsigned* __restrict__ sV, int m,
                          float c, int rev, int o) {
  int lo = o - m; if (lo < 0) lo = 0;
  int hi = o < n ? o : n;
  while (lo < hi) {
    int mid = (lo + hi + 1) >> 1;
    if (decodeU(U[mid - 1]) <= scaledAt(sV, m, o - mid, c, rev)) lo = mid;
    else hi = mid - 1;
  }
  return lo;
}

__global__ void k_splits(const unsigned* __restrict__ pX, const unsigned* __restrict__ pY,
                         const unsigned* __restrict__ sx, const unsigned* __restrict__ sy,
                         int N, int M, int k0, int mB,
                         const float* __restrict__ tbl, int* __restrict__ splits) {
  int b = blockIdx.x * blockDim.x + threadIdx.x;
  if (b >= mB) return;
  int kl = blockIdx.y;
  int kc = gridDim.y;
  float c = tbl[256 + k0 + kl];
  int rev = c < 0.0f ? 1 : 0;
  int Stot = N + M;
  int o = b * MOUT; if (o > Stot) o = Stot;
  const unsigned* U1 = pX + (size_t)kl * N;
  const unsigned* U2 = pY + (size_t)kl * M;
  splits[(size_t)kl * mB + b] = mergeSplit(U1, N, sy, M, c, rev, o);
  splits[((size_t)kc + kl) * mB + b] = mergeSplit(U2, M, sx, N, c, rev, o);
}

__device__ __forceinline__ int ldsSplit(const float* __restrict__ sArr, int aCnt, int bCnt,
                                        int o) {
  int lo = o - bCnt; if (lo < 0) lo = 0;
  int hi = o < aCnt ? o : aCnt;
  while (lo < hi) {
    int mid = (lo + hi + 1) >> 1;
    if (sArr[mid - 1] <= sArr[aCnt + o - mid]) lo = mid;
    else hi = mid - 1;
  }
  return lo;
}

// Branchless 8-output merge via bitonic half-merge.
__device__ __forceinline__ void merge8(const float* __restrict__ sArr, int aCnt, int bCnt,
                                       int la, int lb, float* m) {
  const float FMAX = 3.402823466e38f;
  float a[8], b[8];
#pragma unroll
  for (int j = 0; j < 8; ++j) {
    a[j] = (la + j < aCnt) ? sArr[la + j] : FMAX;
    b[j] = (lb + j < bCnt) ? sArr[aCnt + lb + j] : FMAX;
  }
#pragma unroll
  for (int j = 0; j < 8; ++j) m[j] = fminf(a[j], b[7 - j]);
#pragma unroll
  for (int d = 4; d > 0; d >>= 1) {
#pragma unroll
    for (int i = 0; i < 8; ++i) {
      if ((i & d) == 0 && (i | d) < 8) {
        float lo = fminf(m[i], m[i | d]);
        float hi = fmaxf(m[i], m[i | d]);
        m[i] = lo; m[i | d] = hi;
      }
    }
  }
}

__global__ __launch_bounds__(MBLK) void k_merge(const unsigned* __restrict__ pX,
                                                const unsigned* __restrict__ pY,
                                                const unsigned* __restrict__ sx,
                                                const unsigned* __restrict__ sy,
                                                int N, int M, int k0,
                                                const float* __restrict__ tbl,
                                                const int* __restrict__ splits, int mB,
                                                double* __restrict__ part) {
  __shared__ float sA[MOUT];
  __shared__ float sB[MOUT];
  __shared__ float red[MBLK];
  int kl = blockIdx.y;
  int kc = gridDim.y;
  float c = tbl[256 + k0 + kl];
  int rev = c < 0.0f ? 1 : 0;
  int Stot = N + M;
  int o0 = blockIdx.x * MOUT;
  int outCnt = min(MOUT, Stot - o0);
  const unsigned* U1 = pX + (size_t)kl * N;
  const unsigned* U2 = pY + (size_t)kl * M;
  int tid = threadIdx.x;
  int aLo = splits[(size_t)kl * mB + blockIdx.x];
  int aHi = splits[(size_t)kl * mB + blockIdx.x + 1];
  int a2Lo = splits[((size_t)kc + kl) * mB + blockIdx.x];
  int a2Hi = splits[((size_t)kc + kl) * mB + blockIdx.x + 1];
  int aCnt = aHi - aLo;
  int bLo = o0 - aLo, bCnt = outCnt - aCnt;
  int a2Cnt = a2Hi - a2Lo;
  int b2Lo = o0 - a2Lo, b2Cnt = outCnt - a2Cnt;
  for (int i = tid; i < aCnt; i += MBLK) sA[i] = decodeU(U1[aLo + i]);
  for (int i = tid; i < bCnt; i += MBLK) {
    int j = bLo + i;
    sA[aCnt + i] = c * decodeU(sy[rev ? (M - 1 - j) : j]);
  }
  for (int i = tid; i < a2Cnt; i += MBLK) sB[i] = decodeU(U2[a2Lo + i]);
  for (int i = tid; i < b2Cnt; i += MBLK) {
    int j = b2Lo + i;
    sB[a2Cnt + i] = c * decodeU(sx[rev ? (N - 1 - j) : j]);
  }
  __syncthreads();
  float acc = 0.0f;
  int lo0 = tid * MPT;
  if (lo0 < outCnt) {
    int cnt = min(MPT, outCnt - lo0);
    int la = ldsSplit(sA, aCnt, bCnt, lo0);
    int lb = lo0 - la;
    int la2 = ldsSplit(sB, a2Cnt, b2Cnt, lo0);
    int lb2 = lo0 - la2;
    float mA[8], mB2[8];
    merge8(sA, aCnt, bCnt, la, lb, mA);
    merge8(sB, a2Cnt, b2Cnt, la2, lb2, mB2);
#pragma unroll
    for (int j = 0; j < 8; ++j)
      if (j < cnt) acc += fabsf(mA[j] - mB2[j]);
  }
  red[tid] = acc;
  __syncthreads();
  for (int ofs = MBLK / 2; ofs > 0; ofs >>= 1) {
    if (tid < ofs) red[tid] += red[tid + ofs];
    __syncthreads();
  }
  if (tid == 0) {
    size_t slot = (size_t)(k0 + kl) * gridDim.x + blockIdx.x;
    part[slot] += (double)red[0];
  }
}

__global__ __launch_bounds__(256) void k_final(const double* __restrict__ part, int nSlots,
                                               float* __restrict__ out) {
  __shared__ double red[256];
  int tid = threadIdx.x;
  double s = 0.0;
  for (int i = tid; i < nSlots; i += 256) s += part[i];
  red[tid] = s;
  __syncthreads();
  for (int ofs = 128; ofs > 0; ofs >>= 1) {
    if (tid < ofs) red[tid] += red[tid + ofs];
    __syncthreads();
  }
  if (tid == 0) out[0] = (float)(red[0] / (double)KDIR);
}

extern "C" void kernel_launch(void* const* d_in, const int* in_sizes, int n_in,
                              void* d_out, int out_size, void* d_ws, size_t ws_size,
                              hipStream_t stream) {
  const float* X = (const float*)d_in[0];
  const float* Y = (const float*)d_in[1];
  int N = in_sizes[0] / 2;
  int M = in_sizes[1] / 2;

  char* ws = (char*)d_ws;
  size_t off = 0;
  auto alloc = [&](size_t b) -> void* {
    void* p = ws + off;
    off += (b + 255) & ~(size_t)255;
    return p;
  };
  float* tbl = (float*)alloc(512 * sizeof(float));
  unsigned* sPing = (unsigned*)alloc((size_t)(N + M) * 4);
  unsigned* sPong = (unsigned*)alloc((size_t)(N + M) * 4);

  int Tn = (N + TILE - 1) / TILE;
  int Tm = (M + TILE - 1) / TILE;
  int Tmax = Tn > Tm ? Tn : Tm;
  int mx = N > M ? N : M;
  int mBlocksAll = (N + M + MOUT - 1) / MOUT;
  int mB = mBlocksAll + 1;
  int nSlots = KDIR * mBlocksAll;
  int* splits = (int*)alloc((size_t)2 * KDIR * mB * 4);
  double* part = (double*)alloc((size_t)nSlots * 8);

  size_t perDir = (size_t)(N + M) * 8 + (size_t)4 * 256 * Tmax * 4;
  size_t reserve = (size_t)2 * mx * 8 + (size_t)4 * 256 * Tmax * 4;
  size_t remain = ws_size > off ? ws_size - off : 0;
  remain = remain > reserve ? remain - reserve : 0;
  int Kc = (int)(remain / perDir);
  if (Kc > KDIR) Kc = KDIR;
  if (Kc < 1) Kc = 1;
  int maxSegs = 2 * Kc + 2;
  size_t cntElems = (size_t)maxSegs * 256 * Tmax;
  unsigned* countsA = (unsigned*)alloc(cntElems * 4);
  unsigned* countsB = (unsigned*)alloc(cntElems * 4);
  unsigned* cPing = (unsigned*)alloc(((size_t)Kc * (N + M) + 2 * (size_t)mx) * 4);
  unsigned* cPong = (unsigned*)alloc(((size_t)Kc * (N + M) + 2 * (size_t)mx) * 4);

  k_table<<<1, 256, 0, stream>>>(tbl, part, nSlots);

  // non-fused fallback: classic hist+scan+scatter, single counts buffer
  auto sortJob = [&](unsigned* ping, unsigned* pong, int segs, int L) {
    int T = (L + TILE - 1) / TILE;
    unsigned* s = pong;
    unsigned* d = ping;
    for (int p = 0; p < NPASS; ++p) {
      int shift = 8 * (p + 1);
      if (p > 0)
        k_hist8<<<dim3(T, segs), 256, 0, stream>>>(s, L, T, shift, countsA);
      k_scanSeg<<<segs, 256, 0, stream>>>(countsA, T);
      k_scatter8<<<dim3(T, segs), 256, 0, stream>>>(s, d, L, T, shift, countsA,
                                                    (unsigned*)nullptr, 0);
      unsigned* t = s; s = d; d = t;
    }
  };

  bool fused = (N == M) && (Kc == KDIR);

  if (fused) {
    int segs = 2 * KDIR + 2;
    int T = Tn;
    size_t cntBytes = (size_t)segs * 256 * T * 4;
    // one launch builds all 202 segments (layout: cPong + dir*N)
    k_buildAll<<<dim3(Tn, segs), 256, 0, stream>>>(X, Y, N, tbl, cPong, countsA, T);
    // pass 0: pong -> ping (shift 8), accumulate pass-1 hist into countsB
    hipMemsetAsync(countsB, 0, cntBytes, stream);
    k_scanSeg<<<segs, 256, 0, stream>>>(countsA, T);
    k_scatter8<<<dim3(T, segs), 256, 0, stream>>>(cPong, cPing, N, T, 8, countsA,
                                                  countsB, 16);
    // pass 1: ping -> pong (shift 16), accumulate pass-2 hist into countsA
    k_scanSeg<<<segs, 256, 0, stream>>>(countsB, T);
    hipMemsetAsync(countsA, 0, cntBytes, stream);
    k_scatter8<<<dim3(T, segs), 256, 0, stream>>>(cPing, cPong, N, T, 16, countsB,
                                                  countsA, 24);
    // pass 2: pong -> ping (shift 24), no next hist
    k_scanSeg<<<segs, 256, 0, stream>>>(countsA, T);
    k_scatter8<<<dim3(T, segs), 256, 0, stream>>>(cPong, cPing, N, T, 24, countsA,
                                                  (unsigned*)nullptr, 0);
    unsigned* pX = cPing;
    unsigned* pY = cPing + (size_t)KDIR * N;
    unsigned* dX = cPing + (size_t)2 * KDIR * N;
    unsigned* dY = dX + N;
    k_splits<<<dim3((mB + 255) / 256, KDIR), 256, 0, stream>>>(pX, pY, dX, dY, N, M, 0, mB,
                                                               tbl, splits);
    k_merge<<<dim3(mBlocksAll, KDIR), MBLK, 0, stream>>>(pX, pY, dX, dY, N, M, 0, tbl,
                                                         splits, mB, part);
  } else {
    if (N == M) {
      k_build<<<dim3(Tn, 1), 256, 0, stream>>>(X, N, 100, tbl, sPong, countsA, Tn, 0);
      k_build<<<dim3(Tn, 1), 256, 0, stream>>>(Y, N, 100, tbl, sPong + N, countsA, Tn, 1);
      sortJob(sPing, sPong, 2, N);
    } else {
      k_build<<<dim3(Tn, 1), 256, 0, stream>>>(X, N, 100, tbl, sPong, countsA, Tn, 0);
      sortJob(sPing, sPong, 1, N);
      k_build<<<dim3(Tm, 1), 256, 0, stream>>>(Y, M, 100, tbl, sPong + N, countsA, Tm, 0);
      sortJob(sPing + N, sPong + N, 1, M);
    }
    for (int k0 = 0; k0 < KDIR; k0 += Kc) {
      int kc = (KDIR - k0 < Kc) ? (KDIR - k0) : Kc;
      unsigned* pXin = cPong;
      unsigned* pYin = cPong + (size_t)kc * N;
      unsigned* pX = cPing;
      unsigned* pY = cPing + (size_t)kc * N;
      if (N == M) {
        k_build<<<dim3(Tn, kc), 256, 0, stream>>>(X, N, k0, tbl, pXin, countsA, Tn, 0);
        k_build<<<dim3(Tn, kc), 256, 0, stream>>>(Y, N, k0, tbl, pYin, countsA, Tn, kc);
        sortJob(cPing, cPong, 2 * kc, N);
      } else {
        k_build<<<dim3(Tn, kc), 256, 0, stream>>>(X, N, k0, tbl, pXin, countsA, Tn, 0);
        sortJob(pX, pXin, kc, N);
        k_build<<<dim3(Tm, kc), 256, 0, stream>>>(Y, M, k0, tbl, pYin, countsA, Tm, 0);
        sortJob(pY, pYin, kc, M);
      }
      k_splits<<<dim3((mB + 255) / 256, kc), 256, 0, stream>>>(pX, pY, sPing, sPing + N,
                                                               N, M, k0, mB, tbl, splits);
      k_merge<<<dim3(mBlocksAll, kc), MBLK, 0, stream>>>(pX, pY, sPing, sPing + N, N, M, k0,
                                                         tbl, splits, mB, part);
    }
  }
  k_final<<<1, 256, 0, stream>>>(part, nSlots, (float*)d_out);
}

// Round 17
// 801.144 us; speedup vs baseline: 1.2333x; 1.1382x over previous
//
#include <hip/hip_runtime.h>

#define KDIR 100
#define TILE 4096
#define NPASS 3
#define MBLK 512
#define MOUT 4096
#define MPT 8

struct TrueT  { static constexpr bool value = true; };
struct FalseT { static constexpr bool value = false; };

__device__ __forceinline__ unsigned encodeF(float f) {
  unsigned u = __float_as_uint(f);
  return u ^ ((u >> 31) ? 0xFFFFFFFFu : 0x80000000u);
}
__device__ __forceinline__ float decodeU(unsigned u) {
  return __uint_as_float(u ^ ((u >> 31) ? 0x80000000u : 0xFFFFFFFFu));
}

// counts layout (tile-major, coalesced): counts[(seg*T + tile)*256 + d]

// tbl layout: [0..99]=cos, [128..227]=sin, [256..355]=c=(cos+sin)*invn, [384..483]=invn
// synthetic entry k=100: (0.5, 0.5, invn=1) -> diagonal key 0.5*(x+y)
__global__ void k_table(float* tbl, double* part, int nSlots) {
  int k = threadIdx.x;
  const double PI = 3.14159265358979323846;
  if (k < KDIR) {
    double th = -PI * 0.5 + (double)k * (PI / (double)KDIR);
    float c = (float)cos(th), s = (float)sin(th);
    float invn = 1.0f / (c * c + s * s);
    tbl[k] = c; tbl[128 + k] = s; tbl[256 + k] = (c + s) * invn; tbl[384 + k] = invn;
  }
  if (k == 100) { tbl[100] = 0.5f; tbl[228] = 0.5f; tbl[484] = 1.0f; }
  for (int i = k; i < nSlots; i += 256) part[i] = 0.0;
}

__device__ __forceinline__ void buildTile(const float* __restrict__ p0, int nItems,
                                          float ck, float sk, float inv,
                                          unsigned* __restrict__ d0,
                                          unsigned (*h)[256], int tid) {
  int w = tid >> 6;
  if (nItems == TILE) {
    const float4* p4 = (const float4*)p0;
    uint2* o2 = (uint2*)d0;
#pragma unroll
    for (int i = 0; i < 8; ++i) {
      float4 v = p4[i * 256 + tid];
      unsigned ua = encodeF((v.x * ck + v.y * sk) * inv);
      unsigned ub = encodeF((v.z * ck + v.w * sk) * inv);
      o2[i * 256 + tid] = make_uint2(ua, ub);
      atomicAdd(&h[w][(ua >> 8) & 255u], 1u);
      atomicAdd(&h[w][(ub >> 8) & 255u], 1u);
    }
  } else {
    for (int j = tid; j < nItems; j += 256) {
      float x = p0[2 * j], y = p0[2 * j + 1];
      unsigned u = encodeF((x * ck + y * sk) * inv);
      d0[j] = u;
      atomicAdd(&h[w][(u >> 8) & 255u], 1u);
    }
  }
}

// Fused projection-build + pass-0 hist for ALL 202 segments (fused path).
__global__ __launch_bounds__(256) void k_buildAll(const float* __restrict__ X,
                                                  const float* __restrict__ Y, int n,
                                                  const float* __restrict__ tbl,
                                                  unsigned* __restrict__ dst,
                                                  unsigned* __restrict__ counts, int T) {
  __shared__ unsigned h[4][256];
  int tid = threadIdx.x;
  for (int i = tid; i < 4 * 256; i += 256) ((unsigned*)h)[i] = 0;
  __syncthreads();
  int dir = blockIdx.y;
  int k = (dir < KDIR) ? dir : (dir < 2 * KDIR ? dir - KDIR : KDIR);
  const float* P = (dir < KDIR || dir == 2 * KDIR) ? X : Y;
  float ck = tbl[k], sk = tbl[128 + k], inv = tbl[384 + k];
  int tile = blockIdx.x;
  int start = tile * TILE;
  int nItems = min(TILE, n - start);
  buildTile(P + 2 * (size_t)start, nItems, ck, sk, inv,
            dst + (size_t)dir * n + start, h, tid);
  __syncthreads();
  counts[((size_t)dir * T + tile) * 256 + tid] =
      h[0][tid] + h[1][tid] + h[2][tid] + h[3][tid];
}

// Single-source build (non-fused fallback path).
__global__ __launch_bounds__(256) void k_build(const float* __restrict__ P, int n, int kIdx,
                                               const float* __restrict__ tbl,
                                               unsigned* __restrict__ dst,
                                               unsigned* __restrict__ counts, int T, int seg0) {
  __shared__ unsigned h[4][256];
  int tid = threadIdx.x;
  for (int i = tid; i < 4 * 256; i += 256) ((unsigned*)h)[i] = 0;
  __syncthreads();
  int dir = blockIdx.y;
  int k = kIdx + dir;
  float ck = tbl[k], sk = tbl[128 + k], inv = tbl[384 + k];
  int tile = blockIdx.x;
  int start = tile * TILE;
  int nItems = min(TILE, n - start);
  buildTile(P + 2 * (size_t)start, nItems, ck, sk, inv,
            dst + (size_t)dir * n + start, h, tid);
  __syncthreads();
  counts[((size_t)(seg0 + dir) * T + tile) * 256 + tid] =
      h[0][tid] + h[1][tid] + h[2][tid] + h[3][tid];
}

// Standalone per-pass histogram (non-fused fallback path only).
__global__ __launch_bounds__(256) void k_hist8(const unsigned* __restrict__ keys,
                                               int L, int T, int shift,
                                               unsigned* __restrict__ counts) {
  __shared__ unsigned h[4][256];
  int tid = threadIdx.x;
  int w = tid >> 6;
  for (int i = tid; i < 4 * 256; i += 256) ((unsigned*)h)[i] = 0;
  __syncthreads();
  int seg = blockIdx.y, tile = blockIdx.x;
  const unsigned* base = keys + (size_t)seg * L + (size_t)tile * TILE;
  int nItems = min(TILE, L - tile * TILE);
  if (nItems == TILE) {
    const uint4* b4 = (const uint4*)base;
#pragma unroll
    for (int i = 0; i < 4; ++i) {
      uint4 v = b4[i * 256 + tid];
      atomicAdd(&h[w][(v.x >> shift) & 255u], 1u);
      atomicAdd(&h[w][(v.y >> shift) & 255u], 1u);
      atomicAdd(&h[w][(v.z >> shift) & 255u], 1u);
      atomicAdd(&h[w][(v.w >> shift) & 255u], 1u);
    }
  } else {
    for (int i = tid; i < nItems; i += 256)
      atomicAdd(&h[w][(base[i] >> shift) & 255u], 1u);
  }
  __syncthreads();
  counts[((size_t)seg * T + tile) * 256 + tid] =
      h[0][tid] + h[1][tid] + h[2][tid] + h[3][tid];
}

// Per-segment exclusive scan over (digit-major, tile-minor) order;
// tile-major storage -> all accesses coalesced (fixed i, d=tid consecutive).
__global__ __launch_bounds__(256) void k_scanSeg(unsigned* __restrict__ counts, int T) {
  __shared__ unsigned tot[256];
  unsigned* c = counts + (size_t)blockIdx.x * 256 * T;
  int tid = threadIdx.x;
  unsigned sum = 0;
  for (int i = 0; i < T; ++i) sum += c[i * 256 + tid];
  tot[tid] = sum;
  __syncthreads();
  for (int ofs = 1; ofs < 256; ofs <<= 1) {
    unsigned t = (tid >= ofs) ? tot[tid - ofs] : 0u;
    __syncthreads();
    tot[tid] += t;
    __syncthreads();
  }
  unsigned run = tot[tid] - sum;
  for (int i = 0; i < T; ++i) {
    unsigned v = c[i * 256 + tid];
    c[i * 256 + tid] = run;
    run += v;
  }
}

// 8-bit scatter, STABLE, two-phase, full-tile specialized.
__global__ __launch_bounds__(256) void k_scatter8(const unsigned* __restrict__ src,
                                                  unsigned* __restrict__ dst,
                                                  int L, int T, int shift,
                                                  const unsigned* __restrict__ counts,
                                                  unsigned* __restrict__ nextCounts,
                                                  int shift2) {
  __shared__ unsigned runG[4][4][256];
  __shared__ unsigned diffD[256];
  __shared__ unsigned wsum[4];
  int tid = threadIdx.x;
  int lane = tid & 63, w = tid >> 6;
  int seg = blockIdx.y, tile = blockIdx.x;
  const unsigned* sbase = src + (size_t)seg * L + (size_t)tile * TILE;
  int nItems = min(TILE, L - tile * TILE);
  for (int i = tid; i < 4 * 4 * 256; i += 256) ((unsigned*)runG)[i] = 0;
  __syncthreads();
  unsigned kk[16];
  unsigned rr[16];
  unsigned long long laneLT = (1ull << lane) - 1ull;
  unsigned long long aboveM = ~((laneLT << 1) | 1ull);
  int jbase = w * (TILE / 4);

  auto body = [&](auto FULLC) {
    constexpr bool FULL = decltype(FULLC)::value;
#pragma unroll
    for (int i = 0; i < 16; ++i) {
      int j = jbase + i * 64 + lane;
      kk[i] = (FULL || j < nItems) ? sbase[j] : 0xFFFFFFFFu;
    }
#pragma unroll
    for (int s = 0; s < 4; ++s) {
      unsigned long long mask[4];
      unsigned prev[4];
#pragma unroll
      for (int g = 0; g < 4; ++g) {
        int i = g * 4 + s;
        unsigned d = (kk[i] >> shift) & 255u;
        unsigned long long m = FULL ? ~0ull : __ballot(jbase + i * 64 + lane < nItems);
#pragma unroll
        for (int b = 0; b < 8; ++b) {
          unsigned long long bal = __ballot((d >> b) & 1);
          m &= ((d >> b) & 1) ? bal : ~bal;
        }
        mask[g] = m;
        prev[g] = runG[w][g][d];
      }
#pragma unroll
      for (int g = 0; g < 4; ++g) {
        int i = g * 4 + s;
        if (FULL || jbase + i * 64 + lane < nItems) {
          unsigned d = (kk[i] >> shift) & 255u;
          unsigned r = (unsigned)__popcll(mask[g] & laneLT);
          rr[i] = prev[g] + r;
          if (r == 0) runG[w][g][d] = prev[g] + (unsigned)__popcll(mask[g]);
        }
      }
    }
    __syncthreads();
    {
      unsigned v[16];
#pragma unroll
      for (int w2 = 0; w2 < 4; ++w2)
#pragma unroll
        for (int g2 = 0; g2 < 4; ++g2) v[w2 * 4 + g2] = runG[w2][g2][tid];
      unsigned tot = 0;
#pragma unroll
      for (int i = 0; i < 16; ++i) {
        unsigned t = v[i];
        v[i] = tot;
        tot += t;
      }
      unsigned x = tot;
#pragma unroll
      for (int ofs = 1; ofs < 64; ofs <<= 1) {
        unsigned t = __shfl_up(x, ofs, 64);
        if (lane >= ofs) x += t;
      }
      if (lane == 63) wsum[w] = x;
      __syncthreads();
      unsigned basew = 0;
#pragma unroll
      for (int w2 = 0; w2 < 4; ++w2) basew += (w2 < w) ? wsum[w2] : 0u;
      unsigned localStart = basew + x - tot;
      diffD[tid] = counts[((size_t)seg * T + tile) * 256 + tid] - localStart;
#pragma unroll
      for (int w2 = 0; w2 < 4; ++w2)
#pragma unroll
        for (int g2 = 0; g2 < 4; ++g2)
          runG[w2][g2][tid] = v[w2 * 4 + g2] + localStart;
    }
    __syncthreads();
    unsigned lp[16];
#pragma unroll
    for (int i = 0; i < 16; ++i) {
      unsigned d = (kk[i] >> shift) & 255u;
      lp[i] = runG[w][i >> 2][d] + rr[i];
    }
    __syncthreads();
    unsigned* kbuf = &runG[0][0][0];
#pragma unroll
    for (int i = 0; i < 16; ++i) {
      if (FULL || jbase + i * 64 + lane < nItems) kbuf[lp[i]] = kk[i];
    }
    __syncthreads();
    unsigned* dbase = dst + (size_t)seg * L;
#pragma unroll
    for (int i = 0; i < 16; ++i) {
      int pos = i * 256 + tid;
      bool valid = FULL || pos < nItems;
      unsigned k = 0, g = 0, d2 = 0;
      if (valid) {
        k = kbuf[pos];
        unsigned d = (k >> shift) & 255u;
        g = diffD[d] + (unsigned)pos;
        dbase[g] = k;
        d2 = (k >> shift2) & 255u;
      }
      if (nextCounts) {
        unsigned pid = ((g >> 12) << 8) | d2;
        unsigned prevPid = __shfl_up(pid, 1, 64);
        bool leader = valid && (lane == 0 || pid != prevPid);
        unsigned long long lm = __ballot(leader);
        unsigned long long bounds;
        if (FULL) bounds = lm;
        else bounds = lm | ~__ballot(valid);
        if (leader) {
          unsigned long long above = bounds & aboveM;
          int nxt = above ? __builtin_ctzll(above) : 64;
          atomicAdd(&nextCounts[((size_t)seg * T + (g >> 12)) * 256 + d2],
                    (unsigned)(nxt - lane));
        }
      }
    }
  };
  if (nItems == TILE) body(TrueT{});
  else body(FalseT{});
}

__device__ __forceinline__ float scaledAt(const unsigned* __restrict__ s, int len, int j,
                                          float c, int rev) {
  return c * decodeU(s[rev ? (len - 1 - j) : j]);
}

__device__ int mergeSplit(const unsigned* __restrict__ U, int n,
                          const unsigned* __restrict__ sV, int m,
                          float c, int rev, int o) {
  int lo = o - m; if (lo < 0) lo = 0;
  int hi = o < n ? o : n;
  while (lo < hi) {
    int mid = (lo + hi + 1) >> 1;
    if (decodeU(U[mid - 1]) <= scaledAt(sV, m, o - mid, c, rev)) lo = mid;
    else hi = mid - 1;
  }
  return lo;
}

__global__ void k_splits(const unsigned* __restrict__ pX, const unsigned* __restrict__ pY,
                         const unsigned* __restrict__ sx, const unsigned* __restrict__ sy,
                         int N, int M, int k0, int mB,
                         const float* __restrict__ tbl, int* __restrict__ splits) {
  int b = blockIdx.x * blockDim.x + threadIdx.x;
  if (b >= mB) return;
  int kl = blockIdx.y;
  int kc = gridDim.y;
  float c = tbl[256 + k0 + kl];
  int rev = c < 0.0f ? 1 : 0;
  int Stot = N + M;
  int o = b * MOUT; if (o > Stot) o = Stot;
  const unsigned* U1 = pX + (size_t)kl * N;
  const unsigned* U2 = pY + (size_t)kl * M;
  splits[(size_t)kl * mB + b] = mergeSplit(U1, N, sy, M, c, rev, o);
  splits[((size_t)kc + kl) * mB + b] = mergeSplit(U2, M, sx, N, c, rev, o);
}

__device__ __forceinline__ int ldsSplit(const float* __restrict__ sArr, int aCnt, int bCnt,
                                        int o) {
  int lo = o - bCnt; if (lo < 0) lo = 0;
  int hi = o < aCnt ? o : aCnt;
  while (lo < hi) {
    int mid = (lo + hi + 1) >> 1;
    if (sArr[mid - 1] <= sArr[aCnt + o - mid]) lo = mid;
    else hi = mid - 1;
  }
  return lo;
}

// Branchless 8-output merge via bitonic half-merge.
__device__ __forceinline__ void merge8(const float* __restrict__ sArr, int aCnt, int bCnt,
                                       int la, int lb, float* m) {
  const float FMAX = 3.402823466e38f;
  float a[8], b[8];
#pragma unroll
  for (int j = 0; j < 8; ++j) {
    a[j] = (la + j < aCnt) ? sArr[la + j] : FMAX;
    b[j] = (lb + j < bCnt) ? sArr[aCnt + lb + j] : FMAX;
  }
#pragma unroll
  for (int j = 0; j < 8; ++j) m[j] = fminf(a[j], b[7 - j]);
#pragma unroll
  for (int d = 4; d > 0; d >>= 1) {
#pragma unroll
    for (int i = 0; i < 8; ++i) {
      if ((i & d) == 0 && (i | d) < 8) {
        float lo = fminf(m[i], m[i | d]);
        float hi = fmaxf(m[i], m[i | d]);
        m[i] = lo; m[i | d] = hi;
      }
    }
  }
}

__global__ __launch_bounds__(MBLK) void k_merge(const unsigned* __restrict__ pX,
                                                const unsigned* __restrict__ pY,
                                                const unsigned* __restrict__ sx,
                                                const unsigned* __restrict__ sy,
                                                int N, int M, int k0,
                                                const float* __restrict__ tbl,
                                                const int* __restrict__ splits, int mB,
                                                double* __restrict__ part) {
  __shared__ float sA[MOUT];
  __shared__ float sB[MOUT];
  __shared__ float red[MBLK];
  int kl = blockIdx.y;
  int kc = gridDim.y;
  float c = tbl[256 + k0 + kl];
  int rev = c < 0.0f ? 1 : 0;
  int Stot = N + M;
  int o0 = blockIdx.x * MOUT;
  int outCnt = min(MOUT, Stot - o0);
  const unsigned* U1 = pX + (size_t)kl * N;
  const unsigned* U2 = pY + (size_t)kl * M;
  int tid = threadIdx.x;
  int aLo = splits[(size_t)kl * mB + blockIdx.x];
  int aHi = splits[(size_t)kl * mB + blockIdx.x + 1];
  int a2Lo = splits[((size_t)kc + kl) * mB + blockIdx.x];
  int a2Hi = splits[((size_t)kc + kl) * mB + blockIdx.x + 1];
  int aCnt = aHi - aLo;
  int bLo = o0 - aLo, bCnt = outCnt - aCnt;
  int a2Cnt = a2Hi - a2Lo;
  int b2Lo = o0 - a2Lo, b2Cnt = outCnt - a2Cnt;
  for (int i = tid; i < aCnt; i += MBLK) sA[i] = decodeU(U1[aLo + i]);
  for (int i = tid; i < bCnt; i += MBLK) {
    int j = bLo + i;
    sA[aCnt + i] = c * decodeU(sy[rev ? (M - 1 - j) : j]);
  }
  for (int i = tid; i < a2Cnt; i += MBLK) sB[i] = decodeU(U2[a2Lo + i]);
  for (int i = tid; i < b2Cnt; i += MBLK) {
    int j = b2Lo + i;
    sB[a2Cnt + i] = c * decodeU(sx[rev ? (N - 1 - j) : j]);
  }
  __syncthreads();
  float acc = 0.0f;
  int lo0 = tid * MPT;
  if (lo0 < outCnt) {
    int cnt = min(MPT, outCnt - lo0);
    int la = ldsSplit(sA, aCnt, bCnt, lo0);
    int lb = lo0 - la;
    int la2 = ldsSplit(sB, a2Cnt, b2Cnt, lo0);
    int lb2 = lo0 - la2;
    float mA[8], mB2[8];
    merge8(sA, aCnt, bCnt, la, lb, mA);
    merge8(sB, a2Cnt, b2Cnt, la2, lb2, mB2);
#pragma unroll
    for (int j = 0; j < 8; ++j)
      if (j < cnt) acc += fabsf(mA[j] - mB2[j]);
  }
  red[tid] = acc;
  __syncthreads();
  for (int ofs = MBLK / 2; ofs > 0; ofs >>= 1) {
    if (tid < ofs) red[tid] += red[tid + ofs];
    __syncthreads();
  }
  if (tid == 0) {
    size_t slot = (size_t)(k0 + kl) * gridDim.x + blockIdx.x;
    part[slot] += (double)red[0];
  }
}

__global__ __launch_bounds__(256) void k_final(const double* __restrict__ part, int nSlots,
                                               float* __restrict__ out) {
  __shared__ double red[256];
  int tid = threadIdx.x;
  double s = 0.0;
  for (int i = tid; i < nSlots; i += 256) s += part[i];
  red[tid] = s;
  __syncthreads();
  for (int ofs = 128; ofs > 0; ofs >>= 1) {
    if (tid < ofs) red[tid] += red[tid + ofs];
    __syncthreads();
  }
  if (tid == 0) out[0] = (float)(red[0] / (double)KDIR);
}

extern "C" void kernel_launch(void* const* d_in, const int* in_sizes, int n_in,
                              void* d_out, int out_size, void* d_ws, size_t ws_size,
                              hipStream_t stream) {
  const float* X = (const float*)d_in[0];
  const float* Y = (const float*)d_in[1];
  int N = in_sizes[0] / 2;
  int M = in_sizes[1] / 2;

  char* ws = (char*)d_ws;
  size_t off = 0;
  auto alloc = [&](size_t b) -> void* {
    void* p = ws + off;
    off += (b + 255) & ~(size_t)255;
    return p;
  };
  float* tbl = (float*)alloc(512 * sizeof(float));
  unsigned* sPing = (unsigned*)alloc((size_t)(N + M) * 4);
  unsigned* sPong = (unsigned*)alloc((size_t)(N + M) * 4);

  int Tn = (N + TILE - 1) / TILE;
  int Tm = (M + TILE - 1) / TILE;
  int Tmax = Tn > Tm ? Tn : Tm;
  int mx = N > M ? N : M;
  int mBlocksAll = (N + M + MOUT - 1) / MOUT;
  int mB = mBlocksAll + 1;
  int nSlots = KDIR * mBlocksAll;
  int* splits = (int*)alloc((size_t)2 * KDIR * mB * 4);
  double* part = (double*)alloc((size_t)nSlots * 8);

  size_t perDir = (size_t)(N + M) * 8 + (size_t)4 * 256 * Tmax * 4;
  size_t reserve = (size_t)2 * mx * 8 + (size_t)4 * 256 * Tmax * 4;
  size_t remain = ws_size > off ? ws_size - off : 0;
  remain = remain > reserve ? remain - reserve : 0;
  int Kc = (int)(remain / perDir);
  if (Kc > KDIR) Kc = KDIR;
  if (Kc < 1) Kc = 1;
  int maxSegs = 2 * Kc + 2;
  size_t cntElems = (size_t)maxSegs * 256 * Tmax;
  unsigned* countsA = (unsigned*)alloc(cntElems * 4);
  unsigned* countsB = (unsigned*)alloc(cntElems * 4);
  unsigned* cPing = (unsigned*)alloc(((size_t)Kc * (N + M) + 2 * (size_t)mx) * 4);
  unsigned* cPong = (unsigned*)alloc(((size_t)Kc * (N + M) + 2 * (size_t)mx) * 4);

  k_table<<<1, 256, 0, stream>>>(tbl, part, nSlots);

  // non-fused fallback: classic hist+scan+scatter, single counts buffer
  auto sortJob = [&](unsigned* ping, unsigned* pong, int segs, int L) {
    int T = (L + TILE - 1) / TILE;
    unsigned* s = pong;
    unsigned* d = ping;
    for (int p = 0; p < NPASS; ++p) {
      int shift = 8 * (p + 1);
      if (p > 0)
        k_hist8<<<dim3(T, segs), 256, 0, stream>>>(s, L, T, shift, countsA);
      k_scanSeg<<<segs, 256, 0, stream>>>(countsA, T);
      k_scatter8<<<dim3(T, segs), 256, 0, stream>>>(s, d, L, T, shift, countsA,
                                                    (unsigned*)nullptr, 0);
      unsigned* t = s; s = d; d = t;
    }
  };

  bool fused = (N == M) && (Kc == KDIR);

  if (fused) {
    int segs = 2 * KDIR + 2;
    int T = Tn;
    size_t cntBytes = (size_t)segs * 256 * T * 4;
    k_buildAll<<<dim3(Tn, segs), 256, 0, stream>>>(X, Y, N, tbl, cPong, countsA, T);
    // pass 0: pong -> ping (shift 8), accumulate pass-1 hist into countsB
    hipMemsetAsync(countsB, 0, cntBytes, stream);
    k_scanSeg<<<segs, 256, 0, stream>>>(countsA, T);
    k_scatter8<<<dim3(T, segs), 256, 0, stream>>>(cPong, cPing, N, T, 8, countsA,
                                                  countsB, 16);
    // pass 1: ping -> pong (shift 16), accumulate pass-2 hist into countsA
    k_scanSeg<<<segs, 256, 0, stream>>>(countsB, T);
    hipMemsetAsync(countsA, 0, cntBytes, stream);
    k_scatter8<<<dim3(T, segs), 256, 0, stream>>>(cPing, cPong, N, T, 16, countsB,
                                                  countsA, 24);
    // pass 2: pong -> ping (shift 24), no next hist
    k_scanSeg<<<segs, 256, 0, stream>>>(countsA, T);
    k_scatter8<<<dim3(T, segs), 256, 0, stream>>>(cPong, cPing, N, T, 24, countsA,
                                                  (unsigned*)nullptr, 0);
    unsigned* pX = cPing;
    unsigned* pY = cPing + (size_t)KDIR * N;
    unsigned* dX = cPing + (size_t)2 * KDIR * N;
    unsigned* dY = dX + N;
    k_splits<<<dim3((mB + 255) / 256, KDIR), 256, 0, stream>>>(pX, pY, dX, dY, N, M, 0, mB,
                                                               tbl, splits);
    k_merge<<<dim3(mBlocksAll, KDIR), MBLK, 0, stream>>>(pX, pY, dX, dY, N, M, 0, tbl,
                                                         splits, mB, part);
  } else {
    if (N == M) {
      k_build<<<dim3(Tn, 1), 256, 0, stream>>>(X, N, 100, tbl, sPong, countsA, Tn, 0);
      k_build<<<dim3(Tn, 1), 256, 0, stream>>>(Y, N, 100, tbl, sPong + N, countsA, Tn, 1);
      sortJob(sPing, sPong, 2, N);
    } else {
      k_build<<<dim3(Tn, 1), 256, 0, stream>>>(X, N, 100, tbl, sPong, countsA, Tn, 0);
      sortJob(sPing, sPong, 1, N);
      k_build<<<dim3(Tm, 1), 256, 0, stream>>>(Y, M, 100, tbl, sPong + N, countsA, Tm, 0);
      sortJob(sPing + N, sPong + N, 1, M);
    }
    for (int k0 = 0; k0 < KDIR; k0 += Kc) {
      int kc = (KDIR - k0 < Kc) ? (KDIR - k0) : Kc;
      unsigned* pXin = cPong;
      unsigned* pYin = cPong + (size_t)kc * N;
      unsigned* pX = cPing;
      unsigned* pY = cPing + (size_t)kc * N;
      if (N == M) {
        k_build<<<dim3(Tn, kc), 256, 0, stream>>>(X, N, k0, tbl, pXin, countsA, Tn, 0);
        k_build<<<dim3(Tn, kc), 256, 0, stream>>>(Y, N, k0, tbl, pYin, countsA, Tn, kc);
        sortJob(cPing, cPong, 2 * kc, N);
      } else {
        k_build<<<dim3(Tn, kc), 256, 0, stream>>>(X, N, k0, tbl, pXin, countsA, Tn, 0);
        sortJob(pX, pXin, kc, N);
        k_build<<<dim3(Tm, kc), 256, 0, stream>>>(Y, M, k0, tbl, pYin, countsA, Tm, 0);
        sortJob(pY, pYin, kc, M);
      }
      k_splits<<<dim3((mB + 255) / 256, kc), 256, 0, stream>>>(pX, pY, sPing, sPing + N,
                                                               N, M, k0, mB, tbl, splits);
      k_merge<<<dim3(mBlocksAll, kc), MBLK, 0, stream>>>(pX, pY, sPing, sPing + N, N, M, k0,
                                                         tbl, splits, mB, part);
    }
  }
  k_final<<<1, 256, 0, stream>>>(part, nSlots, (float*)d_out);
}